// Round 9
// baseline (800.014 us; speedup 1.0000x reference)
//
#include <hip/hip_runtime.h>
#include <hip/hip_bf16.h>

#define L_ 2048
#define S_ 2048
#define NB 4
#define E_ 1024
#define H_ 16
#define D_ 64
#define LDT 72   // padded LDS row (bf16 units) for GEMM kernels
#define NCH (S_ / 64)

typedef __attribute__((ext_vector_type(8))) short bf16x8;
typedef __attribute__((ext_vector_type(4))) float f32x4;

__device__ __forceinline__ short f2bf(float f) {
  union { float f; unsigned u; } v; v.f = f;
  unsigned r = v.u + 0x7FFFu + ((v.u >> 16) & 1u);
  return (short)(r >> 16);
}
__device__ __forceinline__ float bf2f(short s) {
  union { unsigned u; float f; } v; v.u = ((unsigned)(unsigned short)s) << 16;
  return v.f;
}
// packed f32x2 -> bf16x2 (RNE, same rounding as f2bf)
__device__ __forceinline__ unsigned cvt_pk_bf16(float lo, float hi) {
  unsigned r;
  asm("v_cvt_pk_bf16_f32 %0, %1, %2" : "=v"(r) : "v"(lo), "v"(hi));
  return r;
}
__device__ __forceinline__ float bfu_lo(unsigned u) {
  union { unsigned u; float f; } v; v.u = u << 16; return v.f;
}
__device__ __forceinline__ float bfu_hi(unsigned u) {
  union { unsigned u; float f; } v; v.u = u & 0xFFFF0000u; return v.f;
}

// LDS-visibility-only barrier: does NOT drain vmcnt (global prefetches survive).
#define LGKM_BARRIER() do {                                   \
    asm volatile("s_waitcnt lgkmcnt(0)" ::: "memory");        \
    __builtin_amdgcn_sched_barrier(0);                        \
    __builtin_amdgcn_s_barrier();                             \
    __builtin_amdgcn_sched_barrier(0);                        \
  } while (0)

// ---------------- kernel 1: weight fp32 -> bf16 ----------------
__global__ void k_convert(const float* __restrict__ wi, const float* __restrict__ wo,
                          short* __restrict__ wqkv, short* __restrict__ wout) {
  const int n1 = 3 * E_ * E_ / 4;
  const int n2 = E_ * E_ / 4;
  const int stride = gridDim.x * blockDim.x;
  for (int i = blockIdx.x * blockDim.x + threadIdx.x; i < n1 + n2; i += stride) {
    const float4* s; short* d; int j;
    if (i < n1) { s = (const float4*)wi; d = wqkv; j = i; }
    else        { s = (const float4*)wo; d = wout; j = i - n1; }
    float4 v = s[j];
    uint2 o; o.x = cvt_pk_bf16(v.x, v.y); o.y = cvt_pk_bf16(v.z, v.w);
    *(uint2*)&d[(size_t)j * 4] = o;
  }
}

// ---------------- kernel 2: fused QKV projection GEMM ----------------
// q pre-scaled by (1/8)*log2(e) so softmax uses exp2 directly.
// V (mat==2) is written directly in blocked-V^T layout [nh][t/32][d][t%32].
__global__ __launch_bounds__(256) void k_qkv(
    const float* __restrict__ qin, const float* __restrict__ kin, const float* __restrict__ vin,
    const short* __restrict__ wbf, const float* __restrict__ bias,
    short* __restrict__ qh, short* __restrict__ kh, short* __restrict__ vt) {
  __shared__ short As[128 * LDT];
  __shared__ short Bs[128 * LDT];
  const int bm = blockIdx.x;
  const int fbase = blockIdx.y * 128;
  const int mat = fbase >> 10;
  const float* __restrict__ A = (mat == 0) ? qin : (mat == 1) ? kin : vin;
  short* __restrict__ dst = (mat == 0) ? qh : (mat == 1) ? kh : vt;
  const float scale = (mat == 0) ? 0.125f * 1.44269504088896f : 1.0f;
  const int tid = threadIdx.x;
  const int lane = tid & 63, wid = tid >> 6;
  const int wr = wid >> 1, wc = wid & 1;
  const int lr = lane & 15, lk = lane >> 4;
  f32x4 acc[4][4] = {};

  for (int kb = 0; kb < E_; kb += 64) {
#pragma unroll
    for (int i = 0; i < 8; ++i) {
      int f4 = i * 256 + tid;
      int row = f4 >> 4, k4 = f4 & 15;
      float4 v = *(const float4*)&A[(size_t)(bm * 128 + row) * E_ + kb + k4 * 4];
      uint2 o; o.x = cvt_pk_bf16(v.x, v.y); o.y = cvt_pk_bf16(v.z, v.w);
      *(uint2*)&As[row * LDT + k4 * 4] = o;
    }
#pragma unroll
    for (int i = 0; i < 4; ++i) {
      int e8 = i * 256 + tid;
      int row = e8 >> 3, k8 = e8 & 7;
      int4 v = *(const int4*)&wbf[(size_t)(fbase + row) * E_ + kb + k8 * 8];
      *(int4*)&Bs[row * LDT + k8 * 8] = v;
    }
    __syncthreads();
#pragma unroll
    for (int kk = 0; kk < 2; ++kk) {
      bf16x8 a[4], b[4];
#pragma unroll
      for (int fi = 0; fi < 4; ++fi)
        a[fi] = *(const bf16x8*)&As[(wr * 64 + fi * 16 + lr) * LDT + kk * 32 + lk * 8];
#pragma unroll
      for (int ci = 0; ci < 4; ++ci)
        b[ci] = *(const bf16x8*)&Bs[(wc * 64 + ci * 16 + lr) * LDT + kk * 32 + lk * 8];
#pragma unroll
      for (int fi = 0; fi < 4; ++fi)
#pragma unroll
        for (int ci = 0; ci < 4; ++ci)
          acc[fi][ci] = __builtin_amdgcn_mfma_f32_16x16x32_bf16(a[fi], b[ci], acc[fi][ci], 0, 0, 0);
    }
    __syncthreads();
  }
#pragma unroll
  for (int ci = 0; ci < 4; ++ci) {
    const int fg = fbase + wc * 64 + ci * 16 + lr;
    const float b = bias[fg];
    const int col = fg & 1023;
    const int h = col >> 6, d = col & 63;
#pragma unroll
    for (int fi = 0; fi < 4; ++fi)
#pragma unroll
      for (int j = 0; j < 4; ++j) {
        int m = bm * 128 + wr * 64 + fi * 16 + lk * 4 + j;
        int t = m >> 2, n = m & 3;
        float vv = (acc[fi][ci][j] + b) * scale;
        size_t base = (size_t)(n * H_ + h) * (L_ * D_);
        size_t idx = (mat == 2)
          ? base + (size_t)(t >> 5) * (D_ * 32) + d * 32 + (t & 31)
          : base + ((size_t)t << 6) + d;
        dst[idx] = f2bf(vv);
      }
  }
}

// ---------------- kernel 3: softmax denominators (reciprocal) ----------------
// reload-after-use K pipeline (no barriers here; adds load cover per st-iter)
__global__ __launch_bounds__(256) void k_stats(
    const short* __restrict__ qh, const short* __restrict__ kh, float* __restrict__ rl) {
  const int nh = blockIdx.y;
  const int qt = blockIdx.x;
  const short* __restrict__ Q = qh + (size_t)nh * L_ * D_;
  const short* __restrict__ K = kh + (size_t)nh * S_ * D_;
  const int tid = threadIdx.x;
  const int lane = tid & 63, wid = tid >> 6;
  const int lr = lane & 15, lk = lane >> 4;
  const int rbase = qt * 128 + wid * 32;
  bf16x8 a[2][2];
#pragma unroll
  for (int ri = 0; ri < 2; ++ri)
#pragma unroll
    for (int kk = 0; kk < 2; ++kk)
      a[ri][kk] = *(const bf16x8*)&Q[(size_t)(rbase + ri * 16 + lr) * D_ + kk * 32 + lk * 8];
  bf16x8 kst[4][2];
#pragma unroll
  for (int ci = 0; ci < 4; ++ci) {
    kst[ci][0] = *(const bf16x8*)&K[(size_t)(ci * 16 + lr) * D_ + lk * 8];
    kst[ci][1] = *(const bf16x8*)&K[(size_t)(ci * 16 + lr) * D_ + 32 + lk * 8];
  }
  float ssum[2][4] = {};
  for (int st = 0; st < S_; st += 64) {
    const int stn = (st + 64 < S_) ? st + 64 : st;
    f32x4 acc[2][4] = {};
#pragma unroll
    for (int ci = 0; ci < 4; ++ci) {
#pragma unroll
      for (int ri = 0; ri < 2; ++ri) {
        acc[ri][ci] = __builtin_amdgcn_mfma_f32_16x16x32_bf16(a[ri][0], kst[ci][0], acc[ri][ci], 0, 0, 0);
        acc[ri][ci] = __builtin_amdgcn_mfma_f32_16x16x32_bf16(a[ri][1], kst[ci][1], acc[ri][ci], 0, 0, 0);
      }
      kst[ci][0] = *(const bf16x8*)&K[(size_t)(stn + ci * 16 + lr) * D_ + lk * 8];
      kst[ci][1] = *(const bf16x8*)&K[(size_t)(stn + ci * 16 + lr) * D_ + 32 + lk * 8];
    }
#pragma unroll
    for (int ri = 0; ri < 2; ++ri)
#pragma unroll
      for (int j = 0; j < 4; ++j) {
        float s = __builtin_amdgcn_exp2f(acc[ri][0][j]) + __builtin_amdgcn_exp2f(acc[ri][1][j]) +
                  __builtin_amdgcn_exp2f(acc[ri][2][j]) + __builtin_amdgcn_exp2f(acc[ri][3][j]);
        s += __shfl_xor(s, 1);
        s += __shfl_xor(s, 2);
        s += __shfl_xor(s, 4);
        s += __shfl_xor(s, 8);
        ssum[ri][j] += s;
      }
  }
  if (lr == 0) {
#pragma unroll
    for (int ri = 0; ri < 2; ++ri)
#pragma unroll
      for (int j = 0; j < 4; ++j)
        rl[(size_t)nh * L_ + rbase + ri * 16 + lk * 4 + j] = 1.0f / ssum[ri][j];
  }
}

// ---------------- kernel 4: attention ----------------
// S-split: grid 512, 1D. xcd=bid&7 -> n=xcd>>1, sh=xcd&1, qt=bid>>3.
// Each block: 16 waves (1 head), 32-row q-tile, s in [sh*1024, sh*1024+1024).
// psl single 64KB -> 2 blocks/CU co-resident (independent barrier domains).
// ctx written as bf16 partial (per sh); attnw columns disjoint per sh.
__global__ __launch_bounds__(1024, 8) void k_attn(
    const short* __restrict__ qh, const short* __restrict__ kh, const short* __restrict__ vt,
    const float* __restrict__ rl, float* __restrict__ attnw, short* __restrict__ ctxp) {
  extern __shared__ char psl[];  // [16 heads][32 rows][128B], byte ^= (row&7)<<4
  const int bid = blockIdx.x;
  const int xcd = bid & 7;            // HW round-robins consecutive ids over XCDs
  const int n = xcd >> 1;             // batch -> XCD pair
  const int sh = xcd & 1;             // s-half -> one XCD (4MB K/V = its L2)
  const int qt = bid >> 3;
  const int tid = threadIdx.x;
  const int h = tid >> 6, lane = tid & 63;
  const int lr = lane & 15, lk = lane >> 4;
  const int rbase = qt * 32;
  const size_t nh = (size_t)(n * H_ + h);
  const short* __restrict__ K = kh + nh * S_ * D_;
  const short* __restrict__ VT = vt + nh * S_ * D_;
  char* const slab0 = psl + h * 4096;

  bf16x8 qf[2][2];
  float rls[2];
  {
    const short* Q = qh + nh * L_ * D_;
#pragma unroll
    for (int li = 0; li < 2; ++li) {
#pragma unroll
      for (int kk = 0; kk < 2; ++kk)
        qf[li][kk] = *(const bf16x8*)&Q[(size_t)(rbase + li * 16 + lr) * D_ + kk * 32 + lk * 8];
      rls[li] = rl[nh * L_ + rbase + li * 16 + lr];
    }
  }
  f32x4 cacc[2][4] = {};
  // mean-phase geometry: 1024 threads cover 32 rows x 64 cols (2 cols each)
  const int mrow = tid >> 5, mc2 = (tid & 31) * 2;
  float* awp = attnw + ((size_t)n * L_ + rbase + mrow) * S_ + mc2;
  const int moff = mrow * 128 + ((mc2 * 2) ^ ((mrow & 7) << 4));  // byte offset

  const int ch0 = sh * (NCH / 2), ch1 = ch0 + NCH / 2;
  for (int ch = ch0; ch < ch1; ++ch) {
    const int st = ch * 64;
    // ---- loads for this chunk: K first (used first), then V
    bf16x8 kf[4][2];
#pragma unroll
    for (int u = 0; u < 4; ++u) {
      kf[u][0] = *(const bf16x8*)&K[(size_t)(st + u * 16 + lr) * D_ + lk * 8];
      kf[u][1] = *(const bf16x8*)&K[(size_t)(st + u * 16 + lr) * D_ + 32 + lk * 8];
    }
    bf16x8 vb[4][2];
#pragma unroll
    for (int b = 0; b < 2; ++b) {
      const size_t sb = (size_t)((st >> 5) + b) * (D_ * 32);
#pragma unroll
      for (int ci = 0; ci < 4; ++ci)
        vb[ci][b] = *(const bf16x8*)&VT[sb + (ci * 16 + lr) * 32 + lk * 8];
    }
    // ---- QK^T (swapped: rows=s, cols=l) per 16-s subtile; p -> swizzled LDS
#pragma unroll
    for (int u = 0; u < 4; ++u) {
#pragma unroll
      for (int li = 0; li < 2; ++li) {
        f32x4 sc = {};
        sc = __builtin_amdgcn_mfma_f32_16x16x32_bf16(kf[u][0], qf[li][0], sc, 0, 0, 0);
        sc = __builtin_amdgcn_mfma_f32_16x16x32_bf16(kf[u][1], qf[li][1], sc, 0, 0, 0);
        uint2 pk;
        pk.x = cvt_pk_bf16(__builtin_amdgcn_exp2f(sc[0]) * rls[li],
                           __builtin_amdgcn_exp2f(sc[1]) * rls[li]);
        pk.y = cvt_pk_bf16(__builtin_amdgcn_exp2f(sc[2]) * rls[li],
                           __builtin_amdgcn_exp2f(sc[3]) * rls[li]);
        const int row = li * 16 + lr;
        *(uint2*)(slab0 + row * 128 + ((u * 32 + lk * 8) ^ ((row & 7) << 4))) = pk;
      }
    }
    // ---- PV from own slab (wave-local RAW, pre-barrier)
#pragma unroll
    for (int b = 0; b < 2; ++b)
#pragma unroll
      for (int li = 0; li < 2; ++li) {
        const int row = li * 16 + lr;
        bf16x8 pa = *(const bf16x8*)(slab0 + row * 128 + ((b * 64 + lk * 16) ^ ((row & 7) << 4)));
#pragma unroll
        for (int ci = 0; ci < 4; ++ci)
          cacc[li][ci] = __builtin_amdgcn_mfma_f32_16x16x32_bf16(pa, vb[ci][b], cacc[li][ci], 0, 0, 0);
      }
    LGKM_BARRIER();  // all heads' p visible
    // ---- head-mean -> attn_weights (same chunk)
    {
      float s0 = 0.f, s1 = 0.f;
#pragma unroll
      for (int hh = 0; hh < 16; ++hh) {
        short2 m = *(const short2*)(psl + hh * 4096 + moff);
        s0 += bf2f(m.x); s1 += bf2f(m.y);
      }
      *(float2*)&awp[st] = make_float2(s0 * 0.0625f, s1 * 0.0625f);
    }
    LGKM_BARRIER();  // mean reads done before next chunk's writes
  }
  // ---- ctx partial write: ctxp[sh] at [l][n][h*64+d] bf16
  short* __restrict__ cp = ctxp + (size_t)sh * (L_ * NB * E_);
#pragma unroll
  for (int li = 0; li < 2; ++li)
#pragma unroll
    for (int ci = 0; ci < 4; ++ci)
#pragma unroll
      for (int j = 0; j < 4; ++j) {
        int row = rbase + li * 16 + lk * 4 + j;
        int d = ci * 16 + lr;
        cp[((size_t)row * NB + n) * E_ + h * 64 + d] = f2bf(cacc[li][ci][j]);
      }
}

// ---------------- kernel 5: output projection (fuses ctx = ctxp0 + ctxp1) ----
__global__ __launch_bounds__(256) void k_out(
    const short* __restrict__ ctxp, const short* __restrict__ wbf,
    const float* __restrict__ bias, float* __restrict__ out) {
  __shared__ short As[128 * LDT];
  __shared__ short Bs[128 * LDT];
  const short* __restrict__ c0 = ctxp;
  const short* __restrict__ c1 = ctxp + (size_t)(L_ * NB * E_);
  const int bm = blockIdx.x, bn = blockIdx.y;
  const int tid = threadIdx.x;
  const int lane = tid & 63, wid = tid >> 6;
  const int wr = wid >> 1, wc = wid & 1;
  const int lr = lane & 15, lk = lane >> 4;
  f32x4 acc[4][4] = {};
  for (int kb = 0; kb < E_; kb += 64) {
#pragma unroll
    for (int i = 0; i < 4; ++i) {
      int e8 = i * 256 + tid;
      int row = e8 >> 3, k8 = e8 & 7;
      size_t idx = (size_t)(bm * 128 + row) * E_ + kb + k8 * 8;
      uint4 va = *(const uint4*)&c0[idx];
      uint4 vc = *(const uint4*)&c1[idx];
      uint4 r;
      r.x = cvt_pk_bf16(bfu_lo(va.x) + bfu_lo(vc.x), bfu_hi(va.x) + bfu_hi(vc.x));
      r.y = cvt_pk_bf16(bfu_lo(va.y) + bfu_lo(vc.y), bfu_hi(va.y) + bfu_hi(vc.y));
      r.z = cvt_pk_bf16(bfu_lo(va.z) + bfu_lo(vc.z), bfu_hi(va.z) + bfu_hi(vc.z));
      r.w = cvt_pk_bf16(bfu_lo(va.w) + bfu_lo(vc.w), bfu_hi(va.w) + bfu_hi(vc.w));
      *(uint4*)&As[row * LDT + k8 * 8] = r;
      int4 vb = *(const int4*)&wbf[(size_t)(bn * 128 + row) * E_ + kb + k8 * 8];
      *(int4*)&Bs[row * LDT + k8 * 8] = vb;
    }
    __syncthreads();
#pragma unroll
    for (int kk = 0; kk < 2; ++kk) {
      bf16x8 a[4], b[4];
#pragma unroll
      for (int fi = 0; fi < 4; ++fi)
        a[fi] = *(const bf16x8*)&As[(wr * 64 + fi * 16 + lr) * LDT + kk * 32 + lk * 8];
#pragma unroll
      for (int ci = 0; ci < 4; ++ci)
        b[ci] = *(const bf16x8*)&Bs[(wc * 64 + ci * 16 + lr) * LDT + kk * 32 + lk * 8];
#pragma unroll
      for (int fi = 0; fi < 4; ++fi)
#pragma unroll
        for (int ci = 0; ci < 4; ++ci)
          acc[fi][ci] = __builtin_amdgcn_mfma_f32_16x16x32_bf16(a[fi], b[ci], acc[fi][ci], 0, 0, 0);
    }
    __syncthreads();
  }
#pragma unroll
  for (int ci = 0; ci < 4; ++ci) {
    int col = bn * 128 + wc * 64 + ci * 16 + lr;
    float b = bias[col];
#pragma unroll
    for (int fi = 0; fi < 4; ++fi)
#pragma unroll
      for (int j = 0; j < 4; ++j) {
        int m = bm * 128 + wr * 64 + fi * 16 + lk * 4 + j;
        out[(size_t)m * E_ + col] = acc[fi][ci][j] + b;
      }
  }
}

extern "C" void kernel_launch(void* const* d_in, const int* in_sizes, int n_in,
                              void* d_out, int out_size, void* d_ws, size_t ws_size,
                              hipStream_t stream) {
  const float* qin = (const float*)d_in[0];
  const float* kin = (const float*)d_in[1];
  const float* vin = (const float*)d_in[2];
  const float* wi  = (const float*)d_in[3];
  const float* bi  = (const float*)d_in[4];
  const float* wo  = (const float*)d_in[5];
  const float* bo  = (const float*)d_in[6];
  float* out = (float*)d_out;                       // (L,NB,E) fp32
  float* attnw = out + (size_t)L_ * NB * E_;        // (NB,L,S) fp32

  short* wqkv = (short*)d_ws;                       // 3E*E bf16
  short* wout = wqkv + (size_t)3 * E_ * E_;         // E*E bf16
  short* qh = wout + (size_t)E_ * E_;               // NB*H*L*D bf16
  short* kh = qh + (size_t)NB * L_ * E_;
  short* vt = kh + (size_t)NB * L_ * E_;            // NB*H*(S/32)*D*32 bf16 (blocked V^T)
  float* rl = (float*)(vt + (size_t)NB * L_ * E_);  // NB*H*L fp32
  short* ctxp = (short*)(rl + (size_t)NB * H_ * L_); // 2 x L*NB*E bf16 partials

  k_convert<<<1024, 256, 0, stream>>>(wi, wo, wqkv, wout);
  k_qkv<<<dim3(64, 24), 256, 0, stream>>>(qin, kin, vin, wqkv, bi, qh, kh, vt);
  k_stats<<<dim3(16, 64), 256, 0, stream>>>(qh, kh, rl);
  k_attn<<<512, 1024, 65536, stream>>>(qh, kh, vt, rl, attnw, ctxp);
  k_out<<<dim3(64, 8), 256, 0, stream>>>(ctxp, wout, bo, out);
}

// Round 10
// 651.330 us; speedup vs baseline: 1.2283x; 1.2283x over previous
//
#include <hip/hip_runtime.h>
#include <hip/hip_bf16.h>

#define L_ 2048
#define S_ 2048
#define NB 4
#define E_ 1024
#define H_ 16
#define D_ 64
#define LDT 72   // padded LDS row (bf16 units) for GEMM kernels
#define NCH (S_ / 64)

typedef __attribute__((ext_vector_type(8))) short bf16x8;
typedef __attribute__((ext_vector_type(4))) float f32x4;

__device__ __forceinline__ short f2bf(float f) {
  union { float f; unsigned u; } v; v.f = f;
  unsigned r = v.u + 0x7FFFu + ((v.u >> 16) & 1u);
  return (short)(r >> 16);
}
__device__ __forceinline__ float bf2f(short s) {
  union { unsigned u; float f; } v; v.u = ((unsigned)(unsigned short)s) << 16;
  return v.f;
}
// packed f32x2 -> bf16x2 (RNE, same rounding as f2bf)
__device__ __forceinline__ unsigned cvt_pk_bf16(float lo, float hi) {
  unsigned r;
  asm("v_cvt_pk_bf16_f32 %0, %1, %2" : "=v"(r) : "v"(lo), "v"(hi));
  return r;
}

// ---------------- kernel 1: weight fp32 -> bf16 ----------------
__global__ void k_convert(const float* __restrict__ wi, const float* __restrict__ wo,
                          short* __restrict__ wqkv, short* __restrict__ wout) {
  const int n1 = 3 * E_ * E_ / 4;
  const int n2 = E_ * E_ / 4;
  const int stride = gridDim.x * blockDim.x;
  for (int i = blockIdx.x * blockDim.x + threadIdx.x; i < n1 + n2; i += stride) {
    const float4* s; short* d; int j;
    if (i < n1) { s = (const float4*)wi; d = wqkv; j = i; }
    else        { s = (const float4*)wo; d = wout; j = i - n1; }
    float4 v = s[j];
    uint2 o; o.x = cvt_pk_bf16(v.x, v.y); o.y = cvt_pk_bf16(v.z, v.w);
    *(uint2*)&d[(size_t)j * 4] = o;
  }
}

// ---------------- kernel 2: fused QKV projection GEMM ----------------
// q pre-scaled by (1/8)*log2(e) so softmax uses exp2 directly.
// V (mat==2) is written directly in blocked-V^T layout [nh][t/32][d][t%32].
__global__ __launch_bounds__(256) void k_qkv(
    const float* __restrict__ qin, const float* __restrict__ kin, const float* __restrict__ vin,
    const short* __restrict__ wbf, const float* __restrict__ bias,
    short* __restrict__ qh, short* __restrict__ kh, short* __restrict__ vt) {
  __shared__ short As[128 * LDT];
  __shared__ short Bs[128 * LDT];
  const int bm = blockIdx.x;
  const int fbase = blockIdx.y * 128;
  const int mat = fbase >> 10;
  const float* __restrict__ A = (mat == 0) ? qin : (mat == 1) ? kin : vin;
  short* __restrict__ dst = (mat == 0) ? qh : (mat == 1) ? kh : vt;
  const float scale = (mat == 0) ? 0.125f * 1.44269504088896f : 1.0f;
  const int tid = threadIdx.x;
  const int lane = tid & 63, wid = tid >> 6;
  const int wr = wid >> 1, wc = wid & 1;
  const int lr = lane & 15, lk = lane >> 4;
  f32x4 acc[4][4] = {};

  for (int kb = 0; kb < E_; kb += 64) {
#pragma unroll
    for (int i = 0; i < 8; ++i) {
      int f4 = i * 256 + tid;
      int row = f4 >> 4, k4 = f4 & 15;
      float4 v = *(const float4*)&A[(size_t)(bm * 128 + row) * E_ + kb + k4 * 4];
      uint2 o; o.x = cvt_pk_bf16(v.x, v.y); o.y = cvt_pk_bf16(v.z, v.w);
      *(uint2*)&As[row * LDT + k4 * 4] = o;
    }
#pragma unroll
    for (int i = 0; i < 4; ++i) {
      int e8 = i * 256 + tid;
      int row = e8 >> 3, k8 = e8 & 7;
      int4 v = *(const int4*)&wbf[(size_t)(fbase + row) * E_ + kb + k8 * 8];
      *(int4*)&Bs[row * LDT + k8 * 8] = v;
    }
    __syncthreads();
#pragma unroll
    for (int kk = 0; kk < 2; ++kk) {
      bf16x8 a[4], b[4];
#pragma unroll
      for (int fi = 0; fi < 4; ++fi)
        a[fi] = *(const bf16x8*)&As[(wr * 64 + fi * 16 + lr) * LDT + kk * 32 + lk * 8];
#pragma unroll
      for (int ci = 0; ci < 4; ++ci)
        b[ci] = *(const bf16x8*)&Bs[(wc * 64 + ci * 16 + lr) * LDT + kk * 32 + lk * 8];
#pragma unroll
      for (int fi = 0; fi < 4; ++fi)
#pragma unroll
        for (int ci = 0; ci < 4; ++ci)
          acc[fi][ci] = __builtin_amdgcn_mfma_f32_16x16x32_bf16(a[fi], b[ci], acc[fi][ci], 0, 0, 0);
    }
    __syncthreads();
  }
#pragma unroll
  for (int ci = 0; ci < 4; ++ci) {
    const int fg = fbase + wc * 64 + ci * 16 + lr;
    const float b = bias[fg];
    const int col = fg & 1023;
    const int h = col >> 6, d = col & 63;
#pragma unroll
    for (int fi = 0; fi < 4; ++fi)
#pragma unroll
      for (int j = 0; j < 4; ++j) {
        int m = bm * 128 + wr * 64 + fi * 16 + lk * 4 + j;
        int t = m >> 2, n = m & 3;
        float vv = (acc[fi][ci][j] + b) * scale;
        size_t base = (size_t)(n * H_ + h) * (L_ * D_);
        size_t idx = (mat == 2)
          ? base + (size_t)(t >> 5) * (D_ * 32) + d * 32 + (t & 31)
          : base + ((size_t)t << 6) + d;
        dst[idx] = f2bf(vv);
      }
  }
}

// ---------------- kernel 3: softmax denominators (reciprocal) ----------------
__global__ __launch_bounds__(256) void k_stats(
    const short* __restrict__ qh, const short* __restrict__ kh, float* __restrict__ rl) {
  const int nh = blockIdx.y;
  const int qt = blockIdx.x;
  const short* __restrict__ Q = qh + (size_t)nh * L_ * D_;
  const short* __restrict__ K = kh + (size_t)nh * S_ * D_;
  const int tid = threadIdx.x;
  const int lane = tid & 63, wid = tid >> 6;
  const int lr = lane & 15, lk = lane >> 4;
  const int rbase = qt * 128 + wid * 32;
  bf16x8 a[2][2];
#pragma unroll
  for (int ri = 0; ri < 2; ++ri)
#pragma unroll
    for (int kk = 0; kk < 2; ++kk)
      a[ri][kk] = *(const bf16x8*)&Q[(size_t)(rbase + ri * 16 + lr) * D_ + kk * 32 + lk * 8];
  bf16x8 kst[4][2];
#pragma unroll
  for (int ci = 0; ci < 4; ++ci) {
    kst[ci][0] = *(const bf16x8*)&K[(size_t)(ci * 16 + lr) * D_ + lk * 8];
    kst[ci][1] = *(const bf16x8*)&K[(size_t)(ci * 16 + lr) * D_ + 32 + lk * 8];
  }
  float ssum[2][4] = {};
  for (int st = 0; st < S_; st += 64) {
    const int stn = (st + 64 < S_) ? st + 64 : st;
    f32x4 acc[2][4] = {};
#pragma unroll
    for (int ci = 0; ci < 4; ++ci) {
#pragma unroll
      for (int ri = 0; ri < 2; ++ri) {
        acc[ri][ci] = __builtin_amdgcn_mfma_f32_16x16x32_bf16(a[ri][0], kst[ci][0], acc[ri][ci], 0, 0, 0);
        acc[ri][ci] = __builtin_amdgcn_mfma_f32_16x16x32_bf16(a[ri][1], kst[ci][1], acc[ri][ci], 0, 0, 0);
      }
      kst[ci][0] = *(const bf16x8*)&K[(size_t)(stn + ci * 16 + lr) * D_ + lk * 8];
      kst[ci][1] = *(const bf16x8*)&K[(size_t)(stn + ci * 16 + lr) * D_ + 32 + lk * 8];
    }
#pragma unroll
    for (int ri = 0; ri < 2; ++ri)
#pragma unroll
      for (int j = 0; j < 4; ++j) {
        float s = __builtin_amdgcn_exp2f(acc[ri][0][j]) + __builtin_amdgcn_exp2f(acc[ri][1][j]) +
                  __builtin_amdgcn_exp2f(acc[ri][2][j]) + __builtin_amdgcn_exp2f(acc[ri][3][j]);
        s += __shfl_xor(s, 1);
        s += __shfl_xor(s, 2);
        s += __shfl_xor(s, 4);
        s += __shfl_xor(s, 8);
        ssum[ri][j] += s;
      }
  }
  if (lr == 0) {
#pragma unroll
    for (int ri = 0; ri < 2; ++ri)
#pragma unroll
      for (int j = 0; j < 4; ++j)
        rl[(size_t)nh * L_ + rbase + ri * 16 + lk * 4 + j] = 1.0f / ssum[ri][j];
  }
}

// ---------------- kernel 4a: attn_weights by recompute ----------------
// attnw[n][l][s] = (1/16) sum_h exp2(q.k)*rl.  Barrier-free, no LDS.
// grid 2048 x 256thr: xcd=bid&7 -> n=xcd>>1, half=xcd&1; r=bid>>3: qt=r&63,
// scq=r>>6; wave's s-chunk = half*1024 + scq*256 + wid*64.
__global__ __launch_bounds__(256) void k_attnw(
    const short* __restrict__ qh, const short* __restrict__ kh,
    const float* __restrict__ rl, float* __restrict__ attnw) {
  const int bid = blockIdx.x;
  const int xcd = bid & 7;
  const int n = xcd >> 1, half = xcd & 1;
  const int r = bid >> 3;
  const int qt = r & 63, scq = r >> 6;
  const int tid = threadIdx.x;
  const int wid = tid >> 6, lane = tid & 63;
  const int lr = lane & 15, lk = lane >> 4;
  const int rbase = qt * 32;
  const int sbase = half * 1024 + scq * 256 + wid * 64;

  f32x4 macc[4][2] = {};  // [u][li]
#pragma unroll 1
  for (int h = 0; h < H_; ++h) {
    const size_t nh = (size_t)(n * H_ + h);
    const short* __restrict__ K = kh + nh * S_ * D_;
    const short* __restrict__ Q = qh + nh * L_ * D_;
    bf16x8 kf[4][2];
#pragma unroll
    for (int u = 0; u < 4; ++u) {
      kf[u][0] = *(const bf16x8*)&K[(size_t)(sbase + u * 16 + lr) * D_ + lk * 8];
      kf[u][1] = *(const bf16x8*)&K[(size_t)(sbase + u * 16 + lr) * D_ + 32 + lk * 8];
    }
    bf16x8 qf[2][2];
    float rls[2];
#pragma unroll
    for (int li = 0; li < 2; ++li) {
      qf[li][0] = *(const bf16x8*)&Q[(size_t)(rbase + li * 16 + lr) * D_ + lk * 8];
      qf[li][1] = *(const bf16x8*)&Q[(size_t)(rbase + li * 16 + lr) * D_ + 32 + lk * 8];
      rls[li] = rl[nh * L_ + rbase + li * 16 + lr];
    }
#pragma unroll
    for (int u = 0; u < 4; ++u)
#pragma unroll
      for (int li = 0; li < 2; ++li) {
        f32x4 sc = {};
        sc = __builtin_amdgcn_mfma_f32_16x16x32_bf16(kf[u][0], qf[li][0], sc, 0, 0, 0);
        sc = __builtin_amdgcn_mfma_f32_16x16x32_bf16(kf[u][1], qf[li][1], sc, 0, 0, 0);
#pragma unroll
        for (int j = 0; j < 4; ++j)
          macc[u][li][j] += __builtin_amdgcn_exp2f(sc[j]) * rls[li];
      }
  }
  // write: lane holds (l = li*16+lr, s = sbase + u*16 + lk*4 + j)
#pragma unroll
  for (int u = 0; u < 4; ++u)
#pragma unroll
    for (int li = 0; li < 2; ++li) {
      float4 o = make_float4(macc[u][li][0] * 0.0625f, macc[u][li][1] * 0.0625f,
                             macc[u][li][2] * 0.0625f, macc[u][li][3] * 0.0625f);
      *(float4*)&attnw[((size_t)n * L_ + rbase + li * 16 + lr) * S_ + sbase + u * 16 + lk * 4] = o;
    }
}

// ---------------- kernel 4b: attention (PV only path) ----------------
// Barrier-free: 256 threads = 4 waves = 4 heads; each wave fully independent
// (own LDS slab, wave-local RAW ordered by compiler lgkmcnt). Full S per wave.
// grid 1024: xcd=bid&7 -> n=xcd>>1, hg0=xcd&1; r=bid>>3: qt=r&63, hg1=(r>>6)&1;
// h = (hg0*2+hg1)*4 + wid.  K/V of 8 heads (4MB) stays in the XCD's L2.
__global__ __launch_bounds__(256) void k_attn(
    const short* __restrict__ qh, const short* __restrict__ kh, const short* __restrict__ vt,
    const float* __restrict__ rl, short* __restrict__ ctx) {
  __shared__ char psl[4][4096];  // per-wave p slab [32 rows][128B], byte ^= (row&7)<<4
  const int bid = blockIdx.x;
  const int xcd = bid & 7;
  const int n = xcd >> 1, hg0 = xcd & 1;
  const int r = bid >> 3;
  const int qt = r & 63, hg1 = (r >> 6) & 1;
  const int tid = threadIdx.x;
  const int wid = tid >> 6, lane = tid & 63;
  const int h = (hg0 * 2 + hg1) * 4 + wid;
  const int lr = lane & 15, lk = lane >> 4;
  const int rbase = qt * 32;
  const size_t nh = (size_t)(n * H_ + h);
  const short* __restrict__ K = kh + nh * S_ * D_;
  const short* __restrict__ VT = vt + nh * S_ * D_;
  char* const slab = psl[wid];

  bf16x8 qf[2][2];
  float rls[2];
  {
    const short* Q = qh + nh * L_ * D_;
#pragma unroll
    for (int li = 0; li < 2; ++li) {
#pragma unroll
      for (int kk = 0; kk < 2; ++kk)
        qf[li][kk] = *(const bf16x8*)&Q[(size_t)(rbase + li * 16 + lr) * D_ + kk * 32 + lk * 8];
      rls[li] = rl[nh * L_ + rbase + li * 16 + lr];
    }
  }
  f32x4 cacc[2][4] = {};

  for (int ch = 0; ch < NCH; ++ch) {
    const int st = ch * 64;
    // ---- loads: K first (used first), then V
    bf16x8 kf[4][2];
#pragma unroll
    for (int u = 0; u < 4; ++u) {
      kf[u][0] = *(const bf16x8*)&K[(size_t)(st + u * 16 + lr) * D_ + lk * 8];
      kf[u][1] = *(const bf16x8*)&K[(size_t)(st + u * 16 + lr) * D_ + 32 + lk * 8];
    }
    bf16x8 vb[4][2];
#pragma unroll
    for (int b = 0; b < 2; ++b) {
      const size_t sb = (size_t)((st >> 5) + b) * (D_ * 32);
#pragma unroll
      for (int ci = 0; ci < 4; ++ci)
        vb[ci][b] = *(const bf16x8*)&VT[sb + (ci * 16 + lr) * 32 + lk * 8];
    }
    // ---- QK^T (swapped: rows=s, cols=l); p -> swizzled slab
#pragma unroll
    for (int u = 0; u < 4; ++u) {
#pragma unroll
      for (int li = 0; li < 2; ++li) {
        f32x4 sc = {};
        sc = __builtin_amdgcn_mfma_f32_16x16x32_bf16(kf[u][0], qf[li][0], sc, 0, 0, 0);
        sc = __builtin_amdgcn_mfma_f32_16x16x32_bf16(kf[u][1], qf[li][1], sc, 0, 0, 0);
        uint2 pk;
        pk.x = cvt_pk_bf16(__builtin_amdgcn_exp2f(sc[0]) * rls[li],
                           __builtin_amdgcn_exp2f(sc[1]) * rls[li]);
        pk.y = cvt_pk_bf16(__builtin_amdgcn_exp2f(sc[2]) * rls[li],
                           __builtin_amdgcn_exp2f(sc[3]) * rls[li]);
        const int row = li * 16 + lr;
        *(uint2*)(slab + row * 128 + ((u * 32 + lk * 8) ^ ((row & 7) << 4))) = pk;
      }
    }
    // ---- PV from own slab (wave-local RAW; no cross-wave barrier needed)
#pragma unroll
    for (int b = 0; b < 2; ++b)
#pragma unroll
      for (int li = 0; li < 2; ++li) {
        const int row = li * 16 + lr;
        bf16x8 pa = *(const bf16x8*)(slab + row * 128 + ((b * 64 + lk * 16) ^ ((row & 7) << 4)));
#pragma unroll
        for (int ci = 0; ci < 4; ++ci)
          cacc[li][ci] = __builtin_amdgcn_mfma_f32_16x16x32_bf16(pa, vb[ci][b], cacc[li][ci], 0, 0, 0);
      }
  }
  // ---- ctx write: [l][n][h*64+d] bf16
#pragma unroll
  for (int li = 0; li < 2; ++li)
#pragma unroll
    for (int ci = 0; ci < 4; ++ci)
#pragma unroll
      for (int j = 0; j < 4; ++j) {
        int row = rbase + li * 16 + lk * 4 + j;
        int d = ci * 16 + lr;
        ctx[((size_t)row * NB + n) * E_ + h * 64 + d] = f2bf(cacc[li][ci][j]);
      }
}

// ---------------- kernel 5: output projection ----------------
__global__ __launch_bounds__(256) void k_out(
    const short* __restrict__ ctxb, const short* __restrict__ wbf,
    const float* __restrict__ bias, float* __restrict__ out) {
  __shared__ short As[128 * LDT];
  __shared__ short Bs[128 * LDT];
  const int bm = blockIdx.x, bn = blockIdx.y;
  const int tid = threadIdx.x;
  const int lane = tid & 63, wid = tid >> 6;
  const int wr = wid >> 1, wc = wid & 1;
  const int lr = lane & 15, lk = lane >> 4;
  f32x4 acc[4][4] = {};
  for (int kb = 0; kb < E_; kb += 64) {
#pragma unroll
    for (int i = 0; i < 4; ++i) {
      int e8 = i * 256 + tid;
      int row = e8 >> 3, k8 = e8 & 7;
      int4 va = *(const int4*)&ctxb[(size_t)(bm * 128 + row) * E_ + kb + k8 * 8];
      *(int4*)&As[row * LDT + k8 * 8] = va;
      int4 vb = *(const int4*)&wbf[(size_t)(bn * 128 + row) * E_ + kb + k8 * 8];
      *(int4*)&Bs[row * LDT + k8 * 8] = vb;
    }
    __syncthreads();
#pragma unroll
    for (int kk = 0; kk < 2; ++kk) {
      bf16x8 a[4], b[4];
#pragma unroll
      for (int fi = 0; fi < 4; ++fi)
        a[fi] = *(const bf16x8*)&As[(wr * 64 + fi * 16 + lr) * LDT + kk * 32 + lk * 8];
#pragma unroll
      for (int ci = 0; ci < 4; ++ci)
        b[ci] = *(const bf16x8*)&Bs[(wc * 64 + ci * 16 + lr) * LDT + kk * 32 + lk * 8];
#pragma unroll
      for (int fi = 0; fi < 4; ++fi)
#pragma unroll
        for (int ci = 0; ci < 4; ++ci)
          acc[fi][ci] = __builtin_amdgcn_mfma_f32_16x16x32_bf16(a[fi], b[ci], acc[fi][ci], 0, 0, 0);
    }
    __syncthreads();
  }
#pragma unroll
  for (int ci = 0; ci < 4; ++ci) {
    int col = bn * 128 + wc * 64 + ci * 16 + lr;
    float b = bias[col];
#pragma unroll
    for (int fi = 0; fi < 4; ++fi)
#pragma unroll
      for (int j = 0; j < 4; ++j) {
        int m = bm * 128 + wr * 64 + fi * 16 + lk * 4 + j;
        out[(size_t)m * E_ + col] = acc[fi][ci][j] + b;
      }
  }
}

extern "C" void kernel_launch(void* const* d_in, const int* in_sizes, int n_in,
                              void* d_out, int out_size, void* d_ws, size_t ws_size,
                              hipStream_t stream) {
  const float* qin = (const float*)d_in[0];
  const float* kin = (const float*)d_in[1];
  const float* vin = (const float*)d_in[2];
  const float* wi  = (const float*)d_in[3];
  const float* bi  = (const float*)d_in[4];
  const float* wo  = (const float*)d_in[5];
  const float* bo  = (const float*)d_in[6];
  float* out = (float*)d_out;                       // (L,NB,E) fp32
  float* attnw = out + (size_t)L_ * NB * E_;        // (NB,L,S) fp32

  short* wqkv = (short*)d_ws;                       // 3E*E bf16
  short* wout = wqkv + (size_t)3 * E_ * E_;         // E*E bf16
  short* qh = wout + (size_t)E_ * E_;               // NB*H*L*D bf16
  short* kh = qh + (size_t)NB * L_ * E_;
  short* vt = kh + (size_t)NB * L_ * E_;            // NB*H*(S/32)*D*32 bf16 (blocked V^T)
  float* rl = (float*)(vt + (size_t)NB * L_ * E_);  // NB*H*L fp32
  short* ctx = (short*)(rl + (size_t)NB * H_ * L_); // L*NB*E bf16

  k_convert<<<1024, 256, 0, stream>>>(wi, wo, wqkv, wout);
  k_qkv<<<dim3(64, 24), 256, 0, stream>>>(qin, kin, vin, wqkv, bi, qh, kh, vt);
  k_stats<<<dim3(16, 64), 256, 0, stream>>>(qh, kh, rl);
  k_attnw<<<2048, 256, 0, stream>>>(qh, kh, rl, attnw);
  k_attn<<<1024, 256, 0, stream>>>(qh, kh, vt, rl, ctx);
  k_out<<<dim3(64, 8), 256, 0, stream>>>(ctx, wout, bo, out);
}

// Round 11
// 495.476 us; speedup vs baseline: 1.6146x; 1.3146x over previous
//
#include <hip/hip_runtime.h>
#include <hip/hip_bf16.h>

#define L_ 2048
#define S_ 2048
#define NB 4
#define E_ 1024
#define H_ 16
#define D_ 64
#define LDT 72   // padded LDS row (bf16 units) for GEMM kernels
#define NCH (S_ / 64)

typedef __attribute__((ext_vector_type(8))) short bf16x8;
typedef __attribute__((ext_vector_type(4))) float f32x4;

__device__ __forceinline__ short f2bf(float f) {
  union { float f; unsigned u; } v; v.f = f;
  unsigned r = v.u + 0x7FFFu + ((v.u >> 16) & 1u);
  return (short)(r >> 16);
}
__device__ __forceinline__ float bf2f(short s) {
  union { unsigned u; float f; } v; v.u = ((unsigned)(unsigned short)s) << 16;
  return v.f;
}
// packed f32x2 -> bf16x2 (RNE, same rounding as f2bf)
__device__ __forceinline__ unsigned cvt_pk_bf16(float lo, float hi) {
  unsigned r;
  asm("v_cvt_pk_bf16_f32 %0, %1, %2" : "=v"(r) : "v"(lo), "v"(hi));
  return r;
}

// LDS-visibility-only barrier: does NOT drain vmcnt (global prefetches survive).
#define LGKM_BARRIER() do {                                   \
    asm volatile("s_waitcnt lgkmcnt(0)" ::: "memory");        \
    __builtin_amdgcn_sched_barrier(0);                        \
    __builtin_amdgcn_s_barrier();                             \
    __builtin_amdgcn_sched_barrier(0);                        \
  } while (0)

// ---------------- kernel 1: weight fp32 -> bf16 ----------------
__global__ void k_convert(const float* __restrict__ wi, const float* __restrict__ wo,
                          short* __restrict__ wqkv, short* __restrict__ wout) {
  const int n1 = 3 * E_ * E_ / 4;
  const int n2 = E_ * E_ / 4;
  const int stride = gridDim.x * blockDim.x;
  for (int i = blockIdx.x * blockDim.x + threadIdx.x; i < n1 + n2; i += stride) {
    const float4* s; short* d; int j;
    if (i < n1) { s = (const float4*)wi; d = wqkv; j = i; }
    else        { s = (const float4*)wo; d = wout; j = i - n1; }
    float4 v = s[j];
    uint2 o; o.x = cvt_pk_bf16(v.x, v.y); o.y = cvt_pk_bf16(v.z, v.w);
    *(uint2*)&d[(size_t)j * 4] = o;
  }
}

// ---------------- kernel 2: fused QKV projection GEMM ----------------
// q pre-scaled by (1/8)*log2(e) so softmax uses exp2 directly.
// V (mat==2) is written directly in blocked-V^T layout [nh][t/32][d][t%32].
__global__ __launch_bounds__(256) void k_qkv(
    const float* __restrict__ qin, const float* __restrict__ kin, const float* __restrict__ vin,
    const short* __restrict__ wbf, const float* __restrict__ bias,
    short* __restrict__ qh, short* __restrict__ kh, short* __restrict__ vt) {
  __shared__ short As[128 * LDT];
  __shared__ short Bs[128 * LDT];
  const int bm = blockIdx.x;
  const int fbase = blockIdx.y * 128;
  const int mat = fbase >> 10;
  const float* __restrict__ A = (mat == 0) ? qin : (mat == 1) ? kin : vin;
  short* __restrict__ dst = (mat == 0) ? qh : (mat == 1) ? kh : vt;
  const float scale = (mat == 0) ? 0.125f * 1.44269504088896f : 1.0f;
  const int tid = threadIdx.x;
  const int lane = tid & 63, wid = tid >> 6;
  const int wr = wid >> 1, wc = wid & 1;
  const int lr = lane & 15, lk = lane >> 4;
  f32x4 acc[4][4] = {};

  for (int kb = 0; kb < E_; kb += 64) {
#pragma unroll
    for (int i = 0; i < 8; ++i) {
      int f4 = i * 256 + tid;
      int row = f4 >> 4, k4 = f4 & 15;
      float4 v = *(const float4*)&A[(size_t)(bm * 128 + row) * E_ + kb + k4 * 4];
      uint2 o; o.x = cvt_pk_bf16(v.x, v.y); o.y = cvt_pk_bf16(v.z, v.w);
      *(uint2*)&As[row * LDT + k4 * 4] = o;
    }
#pragma unroll
    for (int i = 0; i < 4; ++i) {
      int e8 = i * 256 + tid;
      int row = e8 >> 3, k8 = e8 & 7;
      int4 v = *(const int4*)&wbf[(size_t)(fbase + row) * E_ + kb + k8 * 8];
      *(int4*)&Bs[row * LDT + k8 * 8] = v;
    }
    __syncthreads();
#pragma unroll
    for (int kk = 0; kk < 2; ++kk) {
      bf16x8 a[4], b[4];
#pragma unroll
      for (int fi = 0; fi < 4; ++fi)
        a[fi] = *(const bf16x8*)&As[(wr * 64 + fi * 16 + lr) * LDT + kk * 32 + lk * 8];
#pragma unroll
      for (int ci = 0; ci < 4; ++ci)
        b[ci] = *(const bf16x8*)&Bs[(wc * 64 + ci * 16 + lr) * LDT + kk * 32 + lk * 8];
#pragma unroll
      for (int fi = 0; fi < 4; ++fi)
#pragma unroll
        for (int ci = 0; ci < 4; ++ci)
          acc[fi][ci] = __builtin_amdgcn_mfma_f32_16x16x32_bf16(a[fi], b[ci], acc[fi][ci], 0, 0, 0);
    }
    __syncthreads();
  }
#pragma unroll
  for (int ci = 0; ci < 4; ++ci) {
    const int fg = fbase + wc * 64 + ci * 16 + lr;
    const float b = bias[fg];
    const int col = fg & 1023;
    const int h = col >> 6, d = col & 63;
#pragma unroll
    for (int fi = 0; fi < 4; ++fi)
#pragma unroll
      for (int j = 0; j < 4; ++j) {
        int m = bm * 128 + wr * 64 + fi * 16 + lk * 4 + j;
        int t = m >> 2, n = m & 3;
        float vv = (acc[fi][ci][j] + b) * scale;
        size_t base = (size_t)(n * H_ + h) * (L_ * D_);
        size_t idx = (mat == 2)
          ? base + (size_t)(t >> 5) * (D_ * 32) + d * 32 + (t & 31)
          : base + ((size_t)t << 6) + d;
        dst[idx] = f2bf(vv);
      }
  }
}

// ---------------- kernel 3: softmax denominators (reciprocal) ----------------
__global__ __launch_bounds__(256) void k_stats(
    const short* __restrict__ qh, const short* __restrict__ kh, float* __restrict__ rl) {
  const int nh = blockIdx.y;
  const int qt = blockIdx.x;
  const short* __restrict__ Q = qh + (size_t)nh * L_ * D_;
  const short* __restrict__ K = kh + (size_t)nh * S_ * D_;
  const int tid = threadIdx.x;
  const int lane = tid & 63, wid = tid >> 6;
  const int lr = lane & 15, lk = lane >> 4;
  const int rbase = qt * 128 + wid * 32;
  bf16x8 a[2][2];
#pragma unroll
  for (int ri = 0; ri < 2; ++ri)
#pragma unroll
    for (int kk = 0; kk < 2; ++kk)
      a[ri][kk] = *(const bf16x8*)&Q[(size_t)(rbase + ri * 16 + lr) * D_ + kk * 32 + lk * 8];
  bf16x8 kst[4][2];
#pragma unroll
  for (int ci = 0; ci < 4; ++ci) {
    kst[ci][0] = *(const bf16x8*)&K[(size_t)(ci * 16 + lr) * D_ + lk * 8];
    kst[ci][1] = *(const bf16x8*)&K[(size_t)(ci * 16 + lr) * D_ + 32 + lk * 8];
  }
  float ssum[2][4] = {};
  for (int st = 0; st < S_; st += 64) {
    const int stn = (st + 64 < S_) ? st + 64 : st;
    f32x4 acc[2][4] = {};
#pragma unroll
    for (int ci = 0; ci < 4; ++ci) {
#pragma unroll
      for (int ri = 0; ri < 2; ++ri) {
        acc[ri][ci] = __builtin_amdgcn_mfma_f32_16x16x32_bf16(a[ri][0], kst[ci][0], acc[ri][ci], 0, 0, 0);
        acc[ri][ci] = __builtin_amdgcn_mfma_f32_16x16x32_bf16(a[ri][1], kst[ci][1], acc[ri][ci], 0, 0, 0);
      }
      kst[ci][0] = *(const bf16x8*)&K[(size_t)(stn + ci * 16 + lr) * D_ + lk * 8];
      kst[ci][1] = *(const bf16x8*)&K[(size_t)(stn + ci * 16 + lr) * D_ + 32 + lk * 8];
    }
#pragma unroll
    for (int ri = 0; ri < 2; ++ri)
#pragma unroll
      for (int j = 0; j < 4; ++j) {
        float s = __builtin_amdgcn_exp2f(acc[ri][0][j]) + __builtin_amdgcn_exp2f(acc[ri][1][j]) +
                  __builtin_amdgcn_exp2f(acc[ri][2][j]) + __builtin_amdgcn_exp2f(acc[ri][3][j]);
        s += __shfl_xor(s, 1);
        s += __shfl_xor(s, 2);
        s += __shfl_xor(s, 4);
        s += __shfl_xor(s, 8);
        ssum[ri][j] += s;
      }
  }
  if (lr == 0) {
#pragma unroll
    for (int ri = 0; ri < 2; ++ri)
#pragma unroll
      for (int j = 0; j < 4; ++j)
        rl[(size_t)nh * L_ + rbase + ri * 16 + lk * 4 + j] = 1.0f / ssum[ri][j];
  }
}

// ---------------- kernel 4: attention (R8 structure + setprio + b64 mean) ----
// 1D grid 256, XCD decode: n = (bid&7)>>1, qt = (bid>>3)|((bid&1)<<5).
// 1024 threads = 16 waves (1 head each); 64-S chunks; psl dbuf 2x64KB;
// one lgkm-only barrier per chunk (mean of chunk t-1 overlaps compute of t).
__global__ __launch_bounds__(1024) void k_attn(
    const short* __restrict__ qh, const short* __restrict__ kh, const short* __restrict__ vt,
    const float* __restrict__ rl, float* __restrict__ attnw, short* __restrict__ ctx) {
  extern __shared__ char psl[];  // [2][16 heads][32 rows][128B], byte ^= (row&7)<<4
  const int bid = blockIdx.x;
  const int xcd = bid & 7;
  const int n = xcd >> 1;
  const int qt = (bid >> 3) | ((xcd & 1) << 5);
  const int tid = threadIdx.x;
  const int h = tid >> 6, lane = tid & 63;
  const int lr = lane & 15, lk = lane >> 4;
  const int rbase = qt * 32;
  const size_t nh = (size_t)(n * H_ + h);
  const short* __restrict__ K = kh + nh * S_ * D_;
  const short* __restrict__ VT = vt + nh * S_ * D_;
  char* const slab0 = psl + h * 4096;

  bf16x8 qf[2][2];
  float rls[2];
  {
    const short* Q = qh + nh * L_ * D_;
#pragma unroll
    for (int li = 0; li < 2; ++li) {
#pragma unroll
      for (int kk = 0; kk < 2; ++kk)
        qf[li][kk] = *(const bf16x8*)&Q[(size_t)(rbase + li * 16 + lr) * D_ + kk * 32 + lk * 8];
      rls[li] = rl[nh * L_ + rbase + li * 16 + lr];
    }
  }
  f32x4 cacc[2][4] = {};
  // mean-phase geometry: 512 threads cover 32 rows x 64 cols (4 cols each, b64)
  const int mrow = tid >> 4, mc4 = (tid & 15) * 4;   // valid when tid < 512
  float* awp = attnw + ((size_t)n * L_ + rbase + mrow) * S_ + mc4;
  const int moff = mrow * 128 + ((mc4 * 2) ^ ((mrow & 7) << 4));  // byte offset

  for (int ch = 0; ch < NCH; ++ch) {
    const int st = ch * 64;
    char* const sl = slab0 + (ch & 1) * 65536;
    // ---- loads for this chunk: K first (used first), then V
    bf16x8 kf[4][2];
#pragma unroll
    for (int u = 0; u < 4; ++u) {
      kf[u][0] = *(const bf16x8*)&K[(size_t)(st + u * 16 + lr) * D_ + lk * 8];
      kf[u][1] = *(const bf16x8*)&K[(size_t)(st + u * 16 + lr) * D_ + 32 + lk * 8];
    }
    bf16x8 vb[4][2];
#pragma unroll
    for (int b = 0; b < 2; ++b) {
      const size_t sb = (size_t)((st >> 5) + b) * (D_ * 32);
#pragma unroll
      for (int ci = 0; ci < 4; ++ci)
        vb[ci][b] = *(const bf16x8*)&VT[sb + (ci * 16 + lr) * 32 + lk * 8];
    }
    // ---- QK^T (swapped: rows=s, cols=l) per 16-s subtile; p -> swizzled LDS
#pragma unroll
    for (int u = 0; u < 4; ++u) {
#pragma unroll
      for (int li = 0; li < 2; ++li) {
        f32x4 sc = {};
        __builtin_amdgcn_s_setprio(1);
        sc = __builtin_amdgcn_mfma_f32_16x16x32_bf16(kf[u][0], qf[li][0], sc, 0, 0, 0);
        sc = __builtin_amdgcn_mfma_f32_16x16x32_bf16(kf[u][1], qf[li][1], sc, 0, 0, 0);
        __builtin_amdgcn_s_setprio(0);
        uint2 pk;
        pk.x = cvt_pk_bf16(__builtin_amdgcn_exp2f(sc[0]) * rls[li],
                           __builtin_amdgcn_exp2f(sc[1]) * rls[li]);
        pk.y = cvt_pk_bf16(__builtin_amdgcn_exp2f(sc[2]) * rls[li],
                           __builtin_amdgcn_exp2f(sc[3]) * rls[li]);
        const int row = li * 16 + lr;
        *(uint2*)(sl + row * 128 + ((u * 32 + lk * 8) ^ ((row & 7) << 4))) = pk;
      }
    }
    // ---- PV from own slab (wave-local RAW)
#pragma unroll
    for (int b = 0; b < 2; ++b)
#pragma unroll
      for (int li = 0; li < 2; ++li) {
        const int row = li * 16 + lr;
        bf16x8 pa = *(const bf16x8*)(sl + row * 128 + ((b * 64 + lk * 16) ^ ((row & 7) << 4)));
        __builtin_amdgcn_s_setprio(1);
#pragma unroll
        for (int ci = 0; ci < 4; ++ci)
          cacc[li][ci] = __builtin_amdgcn_mfma_f32_16x16x32_bf16(pa, vb[ci][b], cacc[li][ci], 0, 0, 0);
        __builtin_amdgcn_s_setprio(0);
      }
    // ---- head-mean of PREVIOUS chunk (other buffer; overlaps this chunk)
    if (ch > 0 && tid < 512) {
      char* const ms = psl + (((ch & 1) ^ 1)) * 65536;
      float s0 = 0.f, s1 = 0.f, s2 = 0.f, s3 = 0.f;
#pragma unroll
      for (int hh = 0; hh < 16; ++hh) {
        uint2 m = *(const uint2*)(ms + hh * 4096 + moff);
        s0 += bf2f((short)(m.x & 0xFFFF)); s1 += bf2f((short)(m.x >> 16));
        s2 += bf2f((short)(m.y & 0xFFFF)); s3 += bf2f((short)(m.y >> 16));
      }
      *(float4*)&awp[st - 64] = make_float4(s0 * 0.0625f, s1 * 0.0625f,
                                            s2 * 0.0625f, s3 * 0.0625f);
    }
    LGKM_BARRIER();  // publish chunk ch; mean reads of ch-1 complete
  }
  // ---- final chunk's mean (chunk NCH-1 lives in buffer 1)
  if (tid < 512) {
    char* const ms = psl + 65536;
    float s0 = 0.f, s1 = 0.f, s2 = 0.f, s3 = 0.f;
#pragma unroll
    for (int hh = 0; hh < 16; ++hh) {
      uint2 m = *(const uint2*)(ms + hh * 4096 + moff);
      s0 += bf2f((short)(m.x & 0xFFFF)); s1 += bf2f((short)(m.x >> 16));
      s2 += bf2f((short)(m.y & 0xFFFF)); s3 += bf2f((short)(m.y >> 16));
    }
    *(float4*)&awp[S_ - 64] = make_float4(s0 * 0.0625f, s1 * 0.0625f,
                                          s2 * 0.0625f, s3 * 0.0625f);
  }
  // ---- ctx write: [l][n][h*64+d] bf16
#pragma unroll
  for (int li = 0; li < 2; ++li)
#pragma unroll
    for (int ci = 0; ci < 4; ++ci)
#pragma unroll
      for (int j = 0; j < 4; ++j) {
        int row = rbase + li * 16 + lk * 4 + j;
        int d = ci * 16 + lr;
        ctx[((size_t)row * NB + n) * E_ + h * 64 + d] = f2bf(cacc[li][ci][j]);
      }
}

// ---------------- kernel 5: output projection ----------------
__global__ __launch_bounds__(256) void k_out(
    const short* __restrict__ ctxb, const short* __restrict__ wbf,
    const float* __restrict__ bias, float* __restrict__ out) {
  __shared__ short As[128 * LDT];
  __shared__ short Bs[128 * LDT];
  const int bm = blockIdx.x, bn = blockIdx.y;
  const int tid = threadIdx.x;
  const int lane = tid & 63, wid = tid >> 6;
  const int wr = wid >> 1, wc = wid & 1;
  const int lr = lane & 15, lk = lane >> 4;
  f32x4 acc[4][4] = {};
  for (int kb = 0; kb < E_; kb += 64) {
#pragma unroll
    for (int i = 0; i < 4; ++i) {
      int e8 = i * 256 + tid;
      int row = e8 >> 3, k8 = e8 & 7;
      int4 va = *(const int4*)&ctxb[(size_t)(bm * 128 + row) * E_ + kb + k8 * 8];
      *(int4*)&As[row * LDT + k8 * 8] = va;
      int4 vb = *(const int4*)&wbf[(size_t)(bn * 128 + row) * E_ + kb + k8 * 8];
      *(int4*)&Bs[row * LDT + k8 * 8] = vb;
    }
    __syncthreads();
#pragma unroll
    for (int kk = 0; kk < 2; ++kk) {
      bf16x8 a[4], b[4];
#pragma unroll
      for (int fi = 0; fi < 4; ++fi)
        a[fi] = *(const bf16x8*)&As[(wr * 64 + fi * 16 + lr) * LDT + kk * 32 + lk * 8];
#pragma unroll
      for (int ci = 0; ci < 4; ++ci)
        b[ci] = *(const bf16x8*)&Bs[(wc * 64 + ci * 16 + lr) * LDT + kk * 32 + lk * 8];
#pragma unroll
      for (int fi = 0; fi < 4; ++fi)
#pragma unroll
        for (int ci = 0; ci < 4; ++ci)
          acc[fi][ci] = __builtin_amdgcn_mfma_f32_16x16x32_bf16(a[fi], b[ci], acc[fi][ci], 0, 0, 0);
    }
    __syncthreads();
  }
#pragma unroll
  for (int ci = 0; ci < 4; ++ci) {
    int col = bn * 128 + wc * 64 + ci * 16 + lr;
    float b = bias[col];
#pragma unroll
    for (int fi = 0; fi < 4; ++fi)
#pragma unroll
      for (int j = 0; j < 4; ++j) {
        int m = bm * 128 + wr * 64 + fi * 16 + lk * 4 + j;
        out[(size_t)m * E_ + col] = acc[fi][ci][j] + b;
      }
  }
}

extern "C" void kernel_launch(void* const* d_in, const int* in_sizes, int n_in,
                              void* d_out, int out_size, void* d_ws, size_t ws_size,
                              hipStream_t stream) {
  const float* qin = (const float*)d_in[0];
  const float* kin = (const float*)d_in[1];
  const float* vin = (const float*)d_in[2];
  const float* wi  = (const float*)d_in[3];
  const float* bi  = (const float*)d_in[4];
  const float* wo  = (const float*)d_in[5];
  const float* bo  = (const float*)d_in[6];
  float* out = (float*)d_out;                       // (L,NB,E) fp32
  float* attnw = out + (size_t)L_ * NB * E_;        // (NB,L,S) fp32

  short* wqkv = (short*)d_ws;                       // 3E*E bf16
  short* wout = wqkv + (size_t)3 * E_ * E_;         // E*E bf16
  short* qh = wout + (size_t)E_ * E_;               // NB*H*L*D bf16
  short* kh = qh + (size_t)NB * L_ * E_;
  short* vt = kh + (size_t)NB * L_ * E_;            // NB*H*(S/32)*D*32 bf16 (blocked V^T)
  float* rl = (float*)(vt + (size_t)NB * L_ * E_);  // NB*H*L fp32
  short* ctx = (short*)(rl + (size_t)NB * H_ * L_); // L*NB*E bf16

  k_convert<<<1024, 256, 0, stream>>>(wi, wo, wqkv, wout);
  k_qkv<<<dim3(64, 24), 256, 0, stream>>>(qin, kin, vin, wqkv, bi, qh, kh, vt);
  k_stats<<<dim3(16, 64), 256, 0, stream>>>(qh, kh, rl);
  k_attn<<<256, 1024, 131072, stream>>>(qh, kh, vt, rl, attnw, ctx);
  k_out<<<dim3(64, 8), 256, 0, stream>>>(ctx, wout, bo, out);
}

// Round 12
// 475.904 us; speedup vs baseline: 1.6810x; 1.0411x over previous
//
#include <hip/hip_runtime.h>
#include <hip/hip_bf16.h>

#define L_ 2048
#define S_ 2048
#define NB 4
#define E_ 1024
#define H_ 16
#define D_ 64
#define LDT 72   // padded LDS row (bf16 units) for GEMM kernels

typedef __attribute__((ext_vector_type(8))) short bf16x8;
typedef __attribute__((ext_vector_type(4))) float f32x4;

__device__ __forceinline__ short f2bf(float f) {
  union { float f; unsigned u; } v; v.f = f;
  unsigned r = v.u + 0x7FFFu + ((v.u >> 16) & 1u);
  return (short)(r >> 16);
}
__device__ __forceinline__ float bf2f(short s) {
  union { unsigned u; float f; } v; v.u = ((unsigned)(unsigned short)s) << 16;
  return v.f;
}
// packed f32x2 -> bf16x2 (RNE, same rounding as f2bf)
__device__ __forceinline__ unsigned cvt_pk_bf16(float lo, float hi) {
  unsigned r;
  asm("v_cvt_pk_bf16_f32 %0, %1, %2" : "=v"(r) : "v"(lo), "v"(hi));
  return r;
}
__device__ __forceinline__ float bfu_lo(unsigned u) {
  union { unsigned u; float f; } v; v.u = u << 16; return v.f;
}
__device__ __forceinline__ float bfu_hi(unsigned u) {
  union { unsigned u; float f; } v; v.u = u & 0xFFFF0000u; return v.f;
}

// LDS-visibility-only barrier: does NOT drain vmcnt (global prefetches survive).
#define LGKM_BARRIER() do {                                   \
    asm volatile("s_waitcnt lgkmcnt(0)" ::: "memory");        \
    __builtin_amdgcn_sched_barrier(0);                        \
    __builtin_amdgcn_s_barrier();                             \
    __builtin_amdgcn_sched_barrier(0);                        \
  } while (0)

// ---------------- kernel 1: weight fp32 -> bf16 ----------------
__global__ void k_convert(const float* __restrict__ wi, const float* __restrict__ wo,
                          short* __restrict__ wqkv, short* __restrict__ wout) {
  const int n1 = 3 * E_ * E_ / 4;
  const int n2 = E_ * E_ / 4;
  const int stride = gridDim.x * blockDim.x;
  for (int i = blockIdx.x * blockDim.x + threadIdx.x; i < n1 + n2; i += stride) {
    const float4* s; short* d; int j;
    if (i < n1) { s = (const float4*)wi; d = wqkv; j = i; }
    else        { s = (const float4*)wo; d = wout; j = i - n1; }
    float4 v = s[j];
    uint2 o; o.x = cvt_pk_bf16(v.x, v.y); o.y = cvt_pk_bf16(v.z, v.w);
    *(uint2*)&d[(size_t)j * 4] = o;
  }
}

// ---------------- kernel 2: fused QKV projection GEMM ----------------
// q pre-scaled by (1/8)*log2(e) so softmax uses exp2 directly.
// V (mat==2) is written directly in blocked-V^T layout [nh][t/32][d][t%32].
__global__ __launch_bounds__(256) void k_qkv(
    const float* __restrict__ qin, const float* __restrict__ kin, const float* __restrict__ vin,
    const short* __restrict__ wbf, const float* __restrict__ bias,
    short* __restrict__ qh, short* __restrict__ kh, short* __restrict__ vt) {
  __shared__ short As[128 * LDT];
  __shared__ short Bs[128 * LDT];
  const int bm = blockIdx.x;
  const int fbase = blockIdx.y * 128;
  const int mat = fbase >> 10;
  const float* __restrict__ A = (mat == 0) ? qin : (mat == 1) ? kin : vin;
  short* __restrict__ dst = (mat == 0) ? qh : (mat == 1) ? kh : vt;
  const float scale = (mat == 0) ? 0.125f * 1.44269504088896f : 1.0f;
  const int tid = threadIdx.x;
  const int lane = tid & 63, wid = tid >> 6;
  const int wr = wid >> 1, wc = wid & 1;
  const int lr = lane & 15, lk = lane >> 4;
  f32x4 acc[4][4] = {};

  for (int kb = 0; kb < E_; kb += 64) {
#pragma unroll
    for (int i = 0; i < 8; ++i) {
      int f4 = i * 256 + tid;
      int row = f4 >> 4, k4 = f4 & 15;
      float4 v = *(const float4*)&A[(size_t)(bm * 128 + row) * E_ + kb + k4 * 4];
      uint2 o; o.x = cvt_pk_bf16(v.x, v.y); o.y = cvt_pk_bf16(v.z, v.w);
      *(uint2*)&As[row * LDT + k4 * 4] = o;
    }
#pragma unroll
    for (int i = 0; i < 4; ++i) {
      int e8 = i * 256 + tid;
      int row = e8 >> 3, k8 = e8 & 7;
      int4 v = *(const int4*)&wbf[(size_t)(fbase + row) * E_ + kb + k8 * 8];
      *(int4*)&Bs[row * LDT + k8 * 8] = v;
    }
    __syncthreads();
#pragma unroll
    for (int kk = 0; kk < 2; ++kk) {
      bf16x8 a[4], b[4];
#pragma unroll
      for (int fi = 0; fi < 4; ++fi)
        a[fi] = *(const bf16x8*)&As[(wr * 64 + fi * 16 + lr) * LDT + kk * 32 + lk * 8];
#pragma unroll
      for (int ci = 0; ci < 4; ++ci)
        b[ci] = *(const bf16x8*)&Bs[(wc * 64 + ci * 16 + lr) * LDT + kk * 32 + lk * 8];
#pragma unroll
      for (int fi = 0; fi < 4; ++fi)
#pragma unroll
        for (int ci = 0; ci < 4; ++ci)
          acc[fi][ci] = __builtin_amdgcn_mfma_f32_16x16x32_bf16(a[fi], b[ci], acc[fi][ci], 0, 0, 0);
    }
    __syncthreads();
  }
#pragma unroll
  for (int ci = 0; ci < 4; ++ci) {
    const int fg = fbase + wc * 64 + ci * 16 + lr;
    const float b = bias[fg];
    const int col = fg & 1023;
    const int h = col >> 6, d = col & 63;
#pragma unroll
    for (int fi = 0; fi < 4; ++fi)
#pragma unroll
      for (int j = 0; j < 4; ++j) {
        int m = bm * 128 + wr * 64 + fi * 16 + lk * 4 + j;
        int t = m >> 2, n = m & 3;
        float vv = (acc[fi][ci][j] + b) * scale;
        size_t base = (size_t)(n * H_ + h) * (L_ * D_);
        size_t idx = (mat == 2)
          ? base + (size_t)(t >> 5) * (D_ * 32) + d * 32 + (t & 31)
          : base + ((size_t)t << 6) + d;
        dst[idx] = f2bf(vv);
      }
  }
}

// ---------------- kernel 3: softmax denominators (reciprocal) ----------------
__global__ __launch_bounds__(256) void k_stats(
    const short* __restrict__ qh, const short* __restrict__ kh, float* __restrict__ rl) {
  const int nh = blockIdx.y;
  const int qt = blockIdx.x;
  const short* __restrict__ Q = qh + (size_t)nh * L_ * D_;
  const short* __restrict__ K = kh + (size_t)nh * S_ * D_;
  const int tid = threadIdx.x;
  const int lane = tid & 63, wid = tid >> 6;
  const int lr = lane & 15, lk = lane >> 4;
  const int rbase = qt * 128 + wid * 32;
  bf16x8 a[2][2];
#pragma unroll
  for (int ri = 0; ri < 2; ++ri)
#pragma unroll
    for (int kk = 0; kk < 2; ++kk)
      a[ri][kk] = *(const bf16x8*)&Q[(size_t)(rbase + ri * 16 + lr) * D_ + kk * 32 + lk * 8];
  bf16x8 kst[4][2];
#pragma unroll
  for (int ci = 0; ci < 4; ++ci) {
    kst[ci][0] = *(const bf16x8*)&K[(size_t)(ci * 16 + lr) * D_ + lk * 8];
    kst[ci][1] = *(const bf16x8*)&K[(size_t)(ci * 16 + lr) * D_ + 32 + lk * 8];
  }
  float ssum[2][4] = {};
  for (int st = 0; st < S_; st += 64) {
    const int stn = (st + 64 < S_) ? st + 64 : st;
    f32x4 acc[2][4] = {};
#pragma unroll
    for (int ci = 0; ci < 4; ++ci) {
#pragma unroll
      for (int ri = 0; ri < 2; ++ri) {
        acc[ri][ci] = __builtin_amdgcn_mfma_f32_16x16x32_bf16(a[ri][0], kst[ci][0], acc[ri][ci], 0, 0, 0);
        acc[ri][ci] = __builtin_amdgcn_mfma_f32_16x16x32_bf16(a[ri][1], kst[ci][1], acc[ri][ci], 0, 0, 0);
      }
      kst[ci][0] = *(const bf16x8*)&K[(size_t)(stn + ci * 16 + lr) * D_ + lk * 8];
      kst[ci][1] = *(const bf16x8*)&K[(size_t)(stn + ci * 16 + lr) * D_ + 32 + lk * 8];
    }
#pragma unroll
    for (int ri = 0; ri < 2; ++ri)
#pragma unroll
      for (int j = 0; j < 4; ++j) {
        float s = __builtin_amdgcn_exp2f(acc[ri][0][j]) + __builtin_amdgcn_exp2f(acc[ri][1][j]) +
                  __builtin_amdgcn_exp2f(acc[ri][2][j]) + __builtin_amdgcn_exp2f(acc[ri][3][j]);
        s += __shfl_xor(s, 1);
        s += __shfl_xor(s, 2);
        s += __shfl_xor(s, 4);
        s += __shfl_xor(s, 8);
        ssum[ri][j] += s;
      }
  }
  if (lr == 0) {
#pragma unroll
    for (int ri = 0; ri < 2; ++ri)
#pragma unroll
      for (int j = 0; j < 4; ++j)
        rl[(size_t)nh * L_ + rbase + ri * 16 + lk * 4 + j] = 1.0f / ssum[ri][j];
  }
}

// ---------------- kernel 4: attention (R5 body + S-half split) ----------------
// grid 512, 1D: xcd=bid&7 -> n=xcd>>1, sh=xcd&1; qt=bid>>3 (32-row q-tile).
// 512 threads = 8 waves, each wave owns 2 heads; s in [sh*1024, sh*1024+1024).
// psl single 64KB XOR-swizzled; 2 lgkm-only barriers per 64-S chunk.
// 2 blocks/CU co-resident (independent barrier domains hide convoy stalls).
// ctx written as bf16 partial per sh; attnw columns disjoint per sh.
__global__ __launch_bounds__(512) void k_attn(
    const short* __restrict__ qh, const short* __restrict__ kh, const short* __restrict__ vt,
    const float* __restrict__ rl, float* __restrict__ attnw, short* __restrict__ ctxp) {
  __shared__ short psl[16][32][64];  // [head][l][s-chunk], byte ^= (row&7)<<4; 4096 B/head
  const int bid = blockIdx.x;
  const int xcd = bid & 7;
  const int n = xcd >> 1, sh = xcd & 1;
  const int qt = bid >> 3;
  const int tid = threadIdx.x;
  const int wid = tid >> 6, lane = tid & 63;
  const int lr = lane & 15, lk = lane >> 4;
  const int rbase = qt * 32;

  const size_t nh0 = (size_t)(n * H_ + wid * 2);
  const short* __restrict__ Kp[2] = { kh + nh0 * S_ * D_, kh + (nh0 + 1) * S_ * D_ };
  const short* __restrict__ Vp[2] = { vt + nh0 * S_ * D_, vt + (nh0 + 1) * S_ * D_ };
  char* slab[2] = { (char*)&psl[wid * 2][0][0], (char*)&psl[wid * 2 + 1][0][0] };

  bf16x8 qf[2][2][2];   // [hp][li][kk]
  float rls[2][2];
  f32x4 cacc[2][2][4] = {};  // [hp][li][ci]
#pragma unroll
  for (int hp = 0; hp < 2; ++hp) {
    const short* Q = qh + (nh0 + hp) * L_ * D_;
#pragma unroll
    for (int li = 0; li < 2; ++li) {
#pragma unroll
      for (int kk = 0; kk < 2; ++kk)
        qf[hp][li][kk] = *(const bf16x8*)&Q[(size_t)(rbase + li * 16 + lr) * D_ + kk * 32 + lk * 8];
      rls[hp][li] = rl[(nh0 + hp) * L_ + rbase + li * 16 + lr];
    }
  }
  // mean-phase geometry: 512 threads cover 32 rows x 64 cols (4 cols each)
  const int mrow = tid >> 4, mc4 = (tid & 15) * 4;
  float* awp = attnw + ((size_t)n * L_ + rbase + mrow) * S_ + mc4;
  const int mswz = (mc4 * 2) ^ ((mrow & 7) << 4);  // byte offset in row

  const int st0 = sh * 1024;
  for (int st = st0; st < st0 + 1024; st += 64) {
#pragma unroll
    for (int hp = 0; hp < 2; ++hp) {
      const short* __restrict__ K = Kp[hp];
      const short* __restrict__ VT = Vp[hp];
      // ---- loads for this head's 64-S chunk (16 x b128, issued together)
      bf16x8 kf[4][2], vb[4][2];
#pragma unroll
      for (int u = 0; u < 4; ++u)
#pragma unroll
        for (int kk = 0; kk < 2; ++kk)
          kf[u][kk] = *(const bf16x8*)&K[(size_t)(st + u * 16 + lr) * D_ + kk * 32 + lk * 8];
#pragma unroll
      for (int b = 0; b < 2; ++b) {
        const size_t sb = (size_t)((st >> 5) + b) * (D_ * 32);
#pragma unroll
        for (int ci = 0; ci < 4; ++ci)
          vb[ci][b] = *(const bf16x8*)&VT[sb + (ci * 16 + lr) * 32 + lk * 8];
      }
      // ---- QK^T (swapped: rows=s, cols=l)
      f32x4 sacc[4][2] = {};
#pragma unroll
      for (int u = 0; u < 4; ++u)
#pragma unroll
        for (int li = 0; li < 2; ++li) {
          sacc[u][li] = __builtin_amdgcn_mfma_f32_16x16x32_bf16(kf[u][0], qf[hp][li][0], sacc[u][li], 0, 0, 0);
          sacc[u][li] = __builtin_amdgcn_mfma_f32_16x16x32_bf16(kf[u][1], qf[hp][li][1], sacc[u][li], 0, 0, 0);
        }
      // ---- p = exp2(s)*rl -> bf16 -> swizzled LDS (b64 writes)
#pragma unroll
      for (int u = 0; u < 4; ++u)
#pragma unroll
        for (int li = 0; li < 2; ++li) {
          uint2 pk;
          pk.x = cvt_pk_bf16(__builtin_amdgcn_exp2f(sacc[u][li][0]) * rls[hp][li],
                             __builtin_amdgcn_exp2f(sacc[u][li][1]) * rls[hp][li]);
          pk.y = cvt_pk_bf16(__builtin_amdgcn_exp2f(sacc[u][li][2]) * rls[hp][li],
                             __builtin_amdgcn_exp2f(sacc[u][li][3]) * rls[hp][li]);
          const int row = li * 16 + lr;
          *(uint2*)(slab[hp] + row * 128 + (((st & 63) * 0 + u * 32 + lk * 8) ^ ((row & 7) << 4))) = pk;
        }
      // ---- PV from own slab (wave-local RAW)
#pragma unroll
      for (int b = 0; b < 2; ++b)
#pragma unroll
        for (int li = 0; li < 2; ++li) {
          const int row = li * 16 + lr;
          bf16x8 pa = *(const bf16x8*)(slab[hp] + row * 128 + ((b * 64 + lk * 16) ^ ((row & 7) << 4)));
#pragma unroll
          for (int ci = 0; ci < 4; ++ci)
            cacc[hp][li][ci] = __builtin_amdgcn_mfma_f32_16x16x32_bf16(pa, vb[ci][b], cacc[hp][li][ci], 0, 0, 0);
        }
    }
    LGKM_BARRIER();  // all heads' p visible
    // ---- head-mean -> attn_weights (512 threads, 4 cols each)
    {
      float s0 = 0.f, s1 = 0.f, s2 = 0.f, s3 = 0.f;
#pragma unroll
      for (int hh = 0; hh < 16; ++hh) {
        short4 m = *(const short4*)((char*)psl + hh * 4096 + mrow * 128 + mswz);
        s0 += bf2f(m.x); s1 += bf2f(m.y); s2 += bf2f(m.z); s3 += bf2f(m.w);
      }
      *(float4*)&awp[st] = make_float4(s0 * 0.0625f, s1 * 0.0625f, s2 * 0.0625f, s3 * 0.0625f);
    }
    LGKM_BARRIER();  // mean reads done before next chunk's writes
  }
  // ---- ctx partial write: ctxp[sh] at [l][n][h*64+d] bf16
  short* __restrict__ cp = ctxp + (size_t)sh * (L_ * NB * E_);
#pragma unroll
  for (int hp = 0; hp < 2; ++hp)
#pragma unroll
    for (int li = 0; li < 2; ++li)
#pragma unroll
      for (int ci = 0; ci < 4; ++ci)
#pragma unroll
        for (int j = 0; j < 4; ++j) {
          int row = rbase + li * 16 + lk * 4 + j;
          int d = ci * 16 + lr;
          cp[((size_t)row * NB + n) * E_ + (wid * 2 + hp) * 64 + d] = f2bf(cacc[hp][li][ci][j]);
        }
}

// ---------------- kernel 5: output projection (fuses ctx = ctxp0 + ctxp1) ----
__global__ __launch_bounds__(256) void k_out(
    const short* __restrict__ ctxp, const short* __restrict__ wbf,
    const float* __restrict__ bias, float* __restrict__ out) {
  __shared__ short As[128 * LDT];
  __shared__ short Bs[128 * LDT];
  const short* __restrict__ c0 = ctxp;
  const short* __restrict__ c1 = ctxp + (size_t)(L_ * NB * E_);
  const int bm = blockIdx.x, bn = blockIdx.y;
  const int tid = threadIdx.x;
  const int lane = tid & 63, wid = tid >> 6;
  const int wr = wid >> 1, wc = wid & 1;
  const int lr = lane & 15, lk = lane >> 4;
  f32x4 acc[4][4] = {};
  for (int kb = 0; kb < E_; kb += 64) {
#pragma unroll
    for (int i = 0; i < 4; ++i) {
      int e8 = i * 256 + tid;
      int row = e8 >> 3, k8 = e8 & 7;
      size_t idx = (size_t)(bm * 128 + row) * E_ + kb + k8 * 8;
      uint4 va = *(const uint4*)&c0[idx];
      uint4 vc = *(const uint4*)&c1[idx];
      uint4 r;
      r.x = cvt_pk_bf16(bfu_lo(va.x) + bfu_lo(vc.x), bfu_hi(va.x) + bfu_hi(vc.x));
      r.y = cvt_pk_bf16(bfu_lo(va.y) + bfu_lo(vc.y), bfu_hi(va.y) + bfu_hi(vc.y));
      r.z = cvt_pk_bf16(bfu_lo(va.z) + bfu_lo(vc.z), bfu_hi(va.z) + bfu_hi(vc.z));
      r.w = cvt_pk_bf16(bfu_lo(va.w) + bfu_lo(vc.w), bfu_hi(va.w) + bfu_hi(vc.w));
      *(uint4*)&As[row * LDT + k8 * 8] = r;
      int4 vb = *(const int4*)&wbf[(size_t)(bn * 128 + row) * E_ + kb + k8 * 8];
      *(int4*)&Bs[row * LDT + k8 * 8] = vb;
    }
    __syncthreads();
#pragma unroll
    for (int kk = 0; kk < 2; ++kk) {
      bf16x8 a[4], b[4];
#pragma unroll
      for (int fi = 0; fi < 4; ++fi)
        a[fi] = *(const bf16x8*)&As[(wr * 64 + fi * 16 + lr) * LDT + kk * 32 + lk * 8];
#pragma unroll
      for (int ci = 0; ci < 4; ++ci)
        b[ci] = *(const bf16x8*)&Bs[(wc * 64 + ci * 16 + lr) * LDT + kk * 32 + lk * 8];
#pragma unroll
      for (int fi = 0; fi < 4; ++fi)
#pragma unroll
        for (int ci = 0; ci < 4; ++ci)
          acc[fi][ci] = __builtin_amdgcn_mfma_f32_16x16x32_bf16(a[fi], b[ci], acc[fi][ci], 0, 0, 0);
    }
    __syncthreads();
  }
#pragma unroll
  for (int ci = 0; ci < 4; ++ci) {
    int col = bn * 128 + wc * 64 + ci * 16 + lr;
    float b = bias[col];
#pragma unroll
    for (int fi = 0; fi < 4; ++fi)
#pragma unroll
      for (int j = 0; j < 4; ++j) {
        int m = bm * 128 + wr * 64 + fi * 16 + lk * 4 + j;
        out[(size_t)m * E_ + col] = acc[fi][ci][j] + b;
      }
  }
}

extern "C" void kernel_launch(void* const* d_in, const int* in_sizes, int n_in,
                              void* d_out, int out_size, void* d_ws, size_t ws_size,
                              hipStream_t stream) {
  const float* qin = (const float*)d_in[0];
  const float* kin = (const float*)d_in[1];
  const float* vin = (const float*)d_in[2];
  const float* wi  = (const float*)d_in[3];
  const float* bi  = (const float*)d_in[4];
  const float* wo  = (const float*)d_in[5];
  const float* bo  = (const float*)d_in[6];
  float* out = (float*)d_out;                       // (L,NB,E) fp32
  float* attnw = out + (size_t)L_ * NB * E_;        // (NB,L,S) fp32

  short* wqkv = (short*)d_ws;                       // 3E*E bf16
  short* wout = wqkv + (size_t)3 * E_ * E_;         // E*E bf16
  short* qh = wout + (size_t)E_ * E_;               // NB*H*L*D bf16
  short* kh = qh + (size_t)NB * L_ * E_;
  short* vt = kh + (size_t)NB * L_ * E_;            // NB*H*(S/32)*D*32 bf16 (blocked V^T)
  float* rl = (float*)(vt + (size_t)NB * L_ * E_);  // NB*H*L fp32
  short* ctxp = (short*)(rl + (size_t)NB * H_ * L_); // 2 x L*NB*E bf16 partials

  k_convert<<<1024, 256, 0, stream>>>(wi, wo, wqkv, wout);
  k_qkv<<<dim3(64, 24), 256, 0, stream>>>(qin, kin, vin, wqkv, bi, qh, kh, vt);
  k_stats<<<dim3(16, 64), 256, 0, stream>>>(qh, kh, rl);
  k_attn<<<512, 512, 0, stream>>>(qh, kh, vt, rl, attnw, ctxp);
  k_out<<<dim3(64, 8), 256, 0, stream>>>(ctxp, wout, bo, out);
}

// Round 13
// 463.550 us; speedup vs baseline: 1.7258x; 1.0267x over previous
//
#include <hip/hip_runtime.h>
#include <hip/hip_bf16.h>

#define L_ 2048
#define S_ 2048
#define NB 4
#define E_ 1024
#define H_ 16
#define D_ 64
#define NCH (S_ / 64)

typedef __attribute__((ext_vector_type(8))) short bf16x8;
typedef __attribute__((ext_vector_type(4))) float f32x4;

__device__ __forceinline__ short f2bf(float f) {
  union { float f; unsigned u; } v; v.f = f;
  unsigned r = v.u + 0x7FFFu + ((v.u >> 16) & 1u);
  return (short)(r >> 16);
}
__device__ __forceinline__ float bf2f(short s) {
  union { unsigned u; float f; } v; v.u = ((unsigned)(unsigned short)s) << 16;
  return v.f;
}
// packed f32x2 -> bf16x2 (RNE, same rounding as f2bf)
__device__ __forceinline__ unsigned cvt_pk_bf16(float lo, float hi) {
  unsigned r;
  asm("v_cvt_pk_bf16_f32 %0, %1, %2" : "=v"(r) : "v"(lo), "v"(hi));
  return r;
}
// async global->LDS, 16B per lane; LDS dest must be wave-uniform base (HW adds lane*16)
__device__ __forceinline__ void gld16(const void* g, void* l) {
  __builtin_amdgcn_global_load_lds(
      (const __attribute__((address_space(1))) unsigned*)g,
      (__attribute__((address_space(3))) unsigned*)l, 16, 0, 0);
}

// LDS-visibility-only barrier: does NOT drain vmcnt (global prefetches survive).
#define LGKM_BARRIER() do {                                   \
    asm volatile("s_waitcnt lgkmcnt(0)" ::: "memory");        \
    __builtin_amdgcn_sched_barrier(0);                        \
    __builtin_amdgcn_s_barrier();                             \
    __builtin_amdgcn_sched_barrier(0);                        \
  } while (0)

// ---------------- kernel 1: fp32 -> bf16 (weights AND q/k/v activations) -----
__global__ void k_convert(const float* __restrict__ wi, const float* __restrict__ wo,
                          const float* __restrict__ qin, const float* __restrict__ kin,
                          const float* __restrict__ vin,
                          short* __restrict__ wqkv, short* __restrict__ wout,
                          short* __restrict__ xq, short* __restrict__ xk,
                          short* __restrict__ xv) {
  const int n1 = 3 * E_ * E_ / 4;       // wi float4s
  const int n2 = E_ * E_ / 4;           // wo
  const int n3 = L_ * NB * E_ / 4;      // each activation
  const int total = n1 + n2 + 3 * n3;
  const int stride = gridDim.x * blockDim.x;
  for (int i = blockIdx.x * blockDim.x + threadIdx.x; i < total; i += stride) {
    const float* src; short* dst; int j = i;
    if (j < n1) { src = wi; dst = wqkv; }
    else {
      j -= n1;
      if (j < n2) { src = wo; dst = wout; }
      else {
        j -= n2;
        if (j < n3) { src = qin; dst = xq; }
        else {
          j -= n3;
          if (j < n3) { src = kin; dst = xk; }
          else { j -= n3; src = vin; dst = xv; }
        }
      }
    }
    float4 v = ((const float4*)src)[j];
    uint2 o; o.x = cvt_pk_bf16(v.x, v.y); o.y = cvt_pk_bf16(v.z, v.w);
    *(uint2*)&dst[(size_t)j * 4] = o;
  }
}

// ---------------- kernel 2: fused QKV projection GEMM (all-bf16, gload_lds) --
// q pre-scaled by (1/8)*log2(e) so softmax uses exp2 directly.
// V (mat==2) written directly in blocked-V^T layout [nh][t/32][d][t%32].
__global__ __launch_bounds__(256) void k_qkv(
    const short* __restrict__ xq, const short* __restrict__ xk, const short* __restrict__ xv,
    const short* __restrict__ wbf, const float* __restrict__ bias,
    short* __restrict__ qh, short* __restrict__ kh, short* __restrict__ vt) {
  __shared__ short As[128 * 64];
  __shared__ short Bs[128 * 64];
  const int bm = blockIdx.x;
  const int fbase = blockIdx.y * 128;
  const int mat = fbase >> 10;
  const short* __restrict__ A = (mat == 0) ? xq : (mat == 1) ? xk : xv;
  short* __restrict__ dst = (mat == 0) ? qh : (mat == 1) ? kh : vt;
  const float scale = (mat == 0) ? 0.125f * 1.44269504088896f : 1.0f;
  const int tid = threadIdx.x;
  const int lane = tid & 63, wid = tid >> 6;
  const int wr = wid >> 1, wc = wid & 1;
  const int lr = lane & 15, lk = lane >> 4;
  const int srow = lane >> 3, schk = (lane & 7) * 8;  // staging row/elem within 8-row group
  f32x4 acc[4][4] = {};

  for (int kb = 0; kb < E_; kb += 64) {
    // stage A and B tiles via async global->LDS (16B/lane, 8 rows per instr)
#pragma unroll
    for (int i = 0; i < 4; ++i) {
      const int row0 = wid * 32 + i * 8;
      gld16(&A[(size_t)(bm * 128 + row0 + srow) * E_ + kb + schk], &As[row0 * 64]);
      gld16(&wbf[(size_t)(fbase + row0 + srow) * E_ + kb + schk], &Bs[row0 * 64]);
    }
    __syncthreads();
#pragma unroll
    for (int kk = 0; kk < 2; ++kk) {
      bf16x8 a[4], b[4];
#pragma unroll
      for (int fi = 0; fi < 4; ++fi)
        a[fi] = *(const bf16x8*)&As[(wr * 64 + fi * 16 + lr) * 64 + kk * 32 + lk * 8];
#pragma unroll
      for (int ci = 0; ci < 4; ++ci)
        b[ci] = *(const bf16x8*)&Bs[(wc * 64 + ci * 16 + lr) * 64 + kk * 32 + lk * 8];
#pragma unroll
      for (int fi = 0; fi < 4; ++fi)
#pragma unroll
        for (int ci = 0; ci < 4; ++ci)
          acc[fi][ci] = __builtin_amdgcn_mfma_f32_16x16x32_bf16(a[fi], b[ci], acc[fi][ci], 0, 0, 0);
    }
    __syncthreads();
  }
#pragma unroll
  for (int ci = 0; ci < 4; ++ci) {
    const int fg = fbase + wc * 64 + ci * 16 + lr;
    const float b = bias[fg];
    const int col = fg & 1023;
    const int h = col >> 6, d = col & 63;
#pragma unroll
    for (int fi = 0; fi < 4; ++fi)
#pragma unroll
      for (int j = 0; j < 4; ++j) {
        int m = bm * 128 + wr * 64 + fi * 16 + lk * 4 + j;
        int t = m >> 2, n = m & 3;
        float vv = (acc[fi][ci][j] + b) * scale;
        size_t base = (size_t)(n * H_ + h) * (L_ * D_);
        size_t idx = (mat == 2)
          ? base + (size_t)(t >> 5) * (D_ * 32) + d * 32 + (t & 31)
          : base + ((size_t)t << 6) + d;
        dst[idx] = f2bf(vv);
      }
  }
}

// ---------------- kernel 3: softmax denominators (reciprocal) ----------------
__global__ __launch_bounds__(256) void k_stats(
    const short* __restrict__ qh, const short* __restrict__ kh, float* __restrict__ rl) {
  const int nh = blockIdx.y;
  const int qt = blockIdx.x;
  const short* __restrict__ Q = qh + (size_t)nh * L_ * D_;
  const short* __restrict__ K = kh + (size_t)nh * S_ * D_;
  const int tid = threadIdx.x;
  const int lane = tid & 63, wid = tid >> 6;
  const int lr = lane & 15, lk = lane >> 4;
  const int rbase = qt * 128 + wid * 32;
  bf16x8 a[2][2];
#pragma unroll
  for (int ri = 0; ri < 2; ++ri)
#pragma unroll
    for (int kk = 0; kk < 2; ++kk)
      a[ri][kk] = *(const bf16x8*)&Q[(size_t)(rbase + ri * 16 + lr) * D_ + kk * 32 + lk * 8];
  bf16x8 kst[4][2];
#pragma unroll
  for (int ci = 0; ci < 4; ++ci) {
    kst[ci][0] = *(const bf16x8*)&K[(size_t)(ci * 16 + lr) * D_ + lk * 8];
    kst[ci][1] = *(const bf16x8*)&K[(size_t)(ci * 16 + lr) * D_ + 32 + lk * 8];
  }
  float ssum[2][4] = {};
  for (int st = 0; st < S_; st += 64) {
    const int stn = (st + 64 < S_) ? st + 64 : st;
    f32x4 acc[2][4] = {};
#pragma unroll
    for (int ci = 0; ci < 4; ++ci) {
#pragma unroll
      for (int ri = 0; ri < 2; ++ri) {
        acc[ri][ci] = __builtin_amdgcn_mfma_f32_16x16x32_bf16(a[ri][0], kst[ci][0], acc[ri][ci], 0, 0, 0);
        acc[ri][ci] = __builtin_amdgcn_mfma_f32_16x16x32_bf16(a[ri][1], kst[ci][1], acc[ri][ci], 0, 0, 0);
      }
      kst[ci][0] = *(const bf16x8*)&K[(size_t)(stn + ci * 16 + lr) * D_ + lk * 8];
      kst[ci][1] = *(const bf16x8*)&K[(size_t)(stn + ci * 16 + lr) * D_ + 32 + lk * 8];
    }
#pragma unroll
    for (int ri = 0; ri < 2; ++ri)
#pragma unroll
      for (int j = 0; j < 4; ++j) {
        float s = __builtin_amdgcn_exp2f(acc[ri][0][j]) + __builtin_amdgcn_exp2f(acc[ri][1][j]) +
                  __builtin_amdgcn_exp2f(acc[ri][2][j]) + __builtin_amdgcn_exp2f(acc[ri][3][j]);
        s += __shfl_xor(s, 1);
        s += __shfl_xor(s, 2);
        s += __shfl_xor(s, 4);
        s += __shfl_xor(s, 8);
        ssum[ri][j] += s;
      }
  }
  if (lr == 0) {
#pragma unroll
    for (int ri = 0; ri < 2; ++ri)
#pragma unroll
      for (int j = 0; j < 4; ++j)
        rl[(size_t)nh * L_ + rbase + ri * 16 + lk * 4 + j] = 1.0f / ssum[ri][j];
  }
}

// ---------------- kernel 4: attention (R8 config — frozen) ----------------
// 1D grid 256, XCD decode: n=(bid&7)>>1, qt=(bid>>3)|((bid&1)<<5).
// 1024 threads = 16 waves (1 head each); 64-S chunks; psl dbuf 2x64KB;
// one lgkm-only barrier per chunk (mean of chunk t-1 overlaps compute of t).
__global__ __launch_bounds__(1024) void k_attn(
    const short* __restrict__ qh, const short* __restrict__ kh, const short* __restrict__ vt,
    const float* __restrict__ rl, float* __restrict__ attnw, short* __restrict__ ctx) {
  extern __shared__ char psl[];  // [2][16 heads][32 rows][128B], byte ^= (row&7)<<4
  const int bid = blockIdx.x;
  const int xcd = bid & 7;
  const int n = xcd >> 1;
  const int qt = (bid >> 3) | ((xcd & 1) << 5);
  const int tid = threadIdx.x;
  const int h = tid >> 6, lane = tid & 63;
  const int lr = lane & 15, lk = lane >> 4;
  const int rbase = qt * 32;
  const size_t nh = (size_t)(n * H_ + h);
  const short* __restrict__ K = kh + nh * S_ * D_;
  const short* __restrict__ VT = vt + nh * S_ * D_;
  char* const slab0 = psl + h * 4096;

  bf16x8 qf[2][2];
  float rls[2];
  {
    const short* Q = qh + nh * L_ * D_;
#pragma unroll
    for (int li = 0; li < 2; ++li) {
#pragma unroll
      for (int kk = 0; kk < 2; ++kk)
        qf[li][kk] = *(const bf16x8*)&Q[(size_t)(rbase + li * 16 + lr) * D_ + kk * 32 + lk * 8];
      rls[li] = rl[nh * L_ + rbase + li * 16 + lr];
    }
  }
  f32x4 cacc[2][4] = {};
  // mean-phase geometry: 1024 threads cover 32 rows x 64 cols (2 cols each)
  const int mrow = tid >> 5, mc2 = (tid & 31) * 2;
  float* awp = attnw + ((size_t)n * L_ + rbase + mrow) * S_ + mc2;
  const int moff = mrow * 128 + ((mc2 * 2) ^ ((mrow & 7) << 4));  // byte offset

  for (int ch = 0; ch < NCH; ++ch) {
    const int st = ch * 64;
    char* const sl = slab0 + (ch & 1) * 65536;
    // ---- loads for this chunk: K first (used first), then V
    bf16x8 kf[4][2];
#pragma unroll
    for (int u = 0; u < 4; ++u) {
      kf[u][0] = *(const bf16x8*)&K[(size_t)(st + u * 16 + lr) * D_ + lk * 8];
      kf[u][1] = *(const bf16x8*)&K[(size_t)(st + u * 16 + lr) * D_ + 32 + lk * 8];
    }
    bf16x8 vb[4][2];
#pragma unroll
    for (int b = 0; b < 2; ++b) {
      const size_t sb = (size_t)((st >> 5) + b) * (D_ * 32);
#pragma unroll
      for (int ci = 0; ci < 4; ++ci)
        vb[ci][b] = *(const bf16x8*)&VT[sb + (ci * 16 + lr) * 32 + lk * 8];
    }
    // ---- QK^T (swapped: rows=s, cols=l) per 16-s subtile; p -> swizzled LDS
#pragma unroll
    for (int u = 0; u < 4; ++u) {
#pragma unroll
      for (int li = 0; li < 2; ++li) {
        f32x4 sc = {};
        sc = __builtin_amdgcn_mfma_f32_16x16x32_bf16(kf[u][0], qf[li][0], sc, 0, 0, 0);
        sc = __builtin_amdgcn_mfma_f32_16x16x32_bf16(kf[u][1], qf[li][1], sc, 0, 0, 0);
        uint2 pk;
        pk.x = cvt_pk_bf16(__builtin_amdgcn_exp2f(sc[0]) * rls[li],
                           __builtin_amdgcn_exp2f(sc[1]) * rls[li]);
        pk.y = cvt_pk_bf16(__builtin_amdgcn_exp2f(sc[2]) * rls[li],
                           __builtin_amdgcn_exp2f(sc[3]) * rls[li]);
        const int row = li * 16 + lr;
        *(uint2*)(sl + row * 128 + ((u * 32 + lk * 8) ^ ((row & 7) << 4))) = pk;
      }
    }
    // ---- PV from own slab (wave-local RAW)
#pragma unroll
    for (int b = 0; b < 2; ++b)
#pragma unroll
      for (int li = 0; li < 2; ++li) {
        const int row = li * 16 + lr;
        bf16x8 pa = *(const bf16x8*)(sl + row * 128 + ((b * 64 + lk * 16) ^ ((row & 7) << 4)));
#pragma unroll
        for (int ci = 0; ci < 4; ++ci)
          cacc[li][ci] = __builtin_amdgcn_mfma_f32_16x16x32_bf16(pa, vb[ci][b], cacc[li][ci], 0, 0, 0);
      }
    // ---- head-mean of PREVIOUS chunk (other buffer; overlaps this chunk)
    if (ch > 0) {
      char* const ms = psl + (((ch & 1) ^ 1)) * 65536;
      float s0 = 0.f, s1 = 0.f;
#pragma unroll
      for (int hh = 0; hh < 16; ++hh) {
        short2 m = *(const short2*)(ms + hh * 4096 + moff);
        s0 += bf2f(m.x); s1 += bf2f(m.y);
      }
      *(float2*)&awp[st - 64] = make_float2(s0 * 0.0625f, s1 * 0.0625f);
    }
    LGKM_BARRIER();  // publish chunk ch; mean reads of ch-1 complete
  }
  // ---- final chunk's mean (chunk NCH-1 lives in buffer 1)
  {
    char* const ms = psl + 65536;
    float s0 = 0.f, s1 = 0.f;
#pragma unroll
    for (int hh = 0; hh < 16; ++hh) {
      short2 m = *(const short2*)(ms + hh * 4096 + moff);
      s0 += bf2f(m.x); s1 += bf2f(m.y);
    }
    *(float2*)&awp[S_ - 64] = make_float2(s0 * 0.0625f, s1 * 0.0625f);
  }
  // ---- ctx write: [l][n][h*64+d] bf16
#pragma unroll
  for (int li = 0; li < 2; ++li)
#pragma unroll
    for (int ci = 0; ci < 4; ++ci)
#pragma unroll
      for (int j = 0; j < 4; ++j) {
        int row = rbase + li * 16 + lk * 4 + j;
        int d = ci * 16 + lr;
        ctx[((size_t)row * NB + n) * E_ + h * 64 + d] = f2bf(cacc[li][ci][j]);
      }
}

// ---------------- kernel 5: output projection (all-bf16, gload_lds) ---------
__global__ __launch_bounds__(256) void k_out(
    const short* __restrict__ ctxb, const short* __restrict__ wbf,
    const float* __restrict__ bias, float* __restrict__ out) {
  __shared__ short As[128 * 64];
  __shared__ short Bs[128 * 64];
  const int bm = blockIdx.x, bn = blockIdx.y;
  const int tid = threadIdx.x;
  const int lane = tid & 63, wid = tid >> 6;
  const int wr = wid >> 1, wc = wid & 1;
  const int lr = lane & 15, lk = lane >> 4;
  const int srow = lane >> 3, schk = (lane & 7) * 8;
  f32x4 acc[4][4] = {};
  for (int kb = 0; kb < E_; kb += 64) {
#pragma unroll
    for (int i = 0; i < 4; ++i) {
      const int row0 = wid * 32 + i * 8;
      gld16(&ctxb[(size_t)(bm * 128 + row0 + srow) * E_ + kb + schk], &As[row0 * 64]);
      gld16(&wbf[(size_t)(bn * 128 + row0 + srow) * E_ + kb + schk], &Bs[row0 * 64]);
    }
    __syncthreads();
#pragma unroll
    for (int kk = 0; kk < 2; ++kk) {
      bf16x8 a[4], b[4];
#pragma unroll
      for (int fi = 0; fi < 4; ++fi)
        a[fi] = *(const bf16x8*)&As[(wr * 64 + fi * 16 + lr) * 64 + kk * 32 + lk * 8];
#pragma unroll
      for (int ci = 0; ci < 4; ++ci)
        b[ci] = *(const bf16x8*)&Bs[(wc * 64 + ci * 16 + lr) * 64 + kk * 32 + lk * 8];
#pragma unroll
      for (int fi = 0; fi < 4; ++fi)
#pragma unroll
        for (int ci = 0; ci < 4; ++ci)
          acc[fi][ci] = __builtin_amdgcn_mfma_f32_16x16x32_bf16(a[fi], b[ci], acc[fi][ci], 0, 0, 0);
    }
    __syncthreads();
  }
#pragma unroll
  for (int ci = 0; ci < 4; ++ci) {
    int col = bn * 128 + wc * 64 + ci * 16 + lr;
    float b = bias[col];
#pragma unroll
    for (int fi = 0; fi < 4; ++fi)
#pragma unroll
      for (int j = 0; j < 4; ++j) {
        int m = bm * 128 + wr * 64 + fi * 16 + lk * 4 + j;
        out[(size_t)m * E_ + col] = acc[fi][ci][j] + b;
      }
  }
}

extern "C" void kernel_launch(void* const* d_in, const int* in_sizes, int n_in,
                              void* d_out, int out_size, void* d_ws, size_t ws_size,
                              hipStream_t stream) {
  const float* qin = (const float*)d_in[0];
  const float* kin = (const float*)d_in[1];
  const float* vin = (const float*)d_in[2];
  const float* wi  = (const float*)d_in[3];
  const float* bi  = (const float*)d_in[4];
  const float* wo  = (const float*)d_in[5];
  const float* bo  = (const float*)d_in[6];
  float* out = (float*)d_out;                       // (L,NB,E) fp32
  float* attnw = out + (size_t)L_ * NB * E_;        // (NB,L,S) fp32

  short* wqkv = (short*)d_ws;                       // 3E*E bf16
  short* wout = wqkv + (size_t)3 * E_ * E_;         // E*E bf16
  short* qh = wout + (size_t)E_ * E_;               // NB*H*L*D bf16
  short* kh = qh + (size_t)NB * L_ * E_;
  short* vt = kh + (size_t)NB * L_ * E_;            // NB*H*(S/32)*D*32 bf16 (blocked V^T)
  float* rl = (float*)(vt + (size_t)NB * L_ * E_);  // NB*H*L fp32
  short* xq = (short*)(rl + (size_t)NB * H_ * L_);  // L*NB*E bf16 activations
  short* xk = xq + (size_t)L_ * NB * E_;
  short* xv = xk + (size_t)L_ * NB * E_;
  short* ctx = xq;  // alias: xq dead after k_qkv, ctx written by k_attn

  k_convert<<<2048, 256, 0, stream>>>(wi, wo, qin, kin, vin, wqkv, wout, xq, xk, xv);
  k_qkv<<<dim3(64, 24), 256, 0, stream>>>(xq, xk, xv, wqkv, bi, qh, kh, vt);
  k_stats<<<dim3(16, 64), 256, 0, stream>>>(qh, kh, rl);
  k_attn<<<256, 1024, 131072, stream>>>(qh, kh, vt, rl, attnw, ctx);
  k_out<<<dim3(64, 8), 256, 0, stream>>>(ctx, wout, bo, out);
}